// Round 14
// baseline (1017.412 us; speedup 1.0000x reference)
//
#include <hip/hip_runtime.h>

#define TLEN 300
#define THETA 10.0f
#define REF_DECAY 0.36787944117144233f
#define NR 4  // independent rows per lane (ILP to hide the serial-chain latency)

// Alpha-kernel recurrence constants: eps[k] = C*k*R^k truncated at k<100.
// y[t] = C*QA[t] - C*R^100*QB[t] - 100*C*R^100*PB[t]; (PA,QA) on x[t], (PB,QB) on x[t-100]:
// P[t] = R*P[t-1] + x[t];  Q[t] = R*(Q[t-1] + P[t-1]).
#define R_ 0.9048374180359595732
#define C_ 0.2718281828459045235
#define R100_ 4.5399929762484852e-05
#define RF_ ((float)R_)
#define CR100F_ ((float)(C_ * R100_))
#define C100R100F_ ((float)(100.0 * C_ * R100_))

// spike bit from `age` steps ago (0 = current). Zero if age<0 or beyond history.
__device__ __forceinline__ float bit_at(unsigned h0, unsigned h1, unsigned h2, unsigned h3,
                                        int age) {
  if (age < 0 || age > 127) return 0.f;
  unsigned wsel;
  switch (age >> 5) {
    case 0: wsel = h0; break;
    case 1: wsel = h1; break;
    case 2: wsel = h2; break;
    default: wsel = h3; break;
  }
  return (float)((wsel >> (age & 31)) & 1u);
}

// per-row psp->spike->psp step, state arrays indexed by compile-time J
#define PSPSUBJ(J, XA, XB, YO)                                                          \
  {                                                                                     \
    QA1[J] = R_ * (QA1[J] + PA1[J]); PA1[J] = R_ * PA1[J] + (double)(XA);               \
    QB1[J] = RF_ * (QB1[J] + PB1[J]); PB1[J] = RF_ * PB1[J] + (XB);                     \
    float u = (float)(C_ * QA1[J]) - (CR100F_ * QB1[J] + C100R100F_ * PB1[J]);          \
    float v = u + ref[J] - THETA;                                                       \
    float sp = (v >= 0.f) ? 1.f : 0.f;                                                  \
    ref[J] = REF_DECAY * ref[J] - 20.0f * sp;                                           \
    h3[J] = (h3[J] << 1) | (h2[J] >> 31); h2[J] = (h2[J] << 1) | (h1[J] >> 31);         \
    h1[J] = (h1[J] << 1) | (h0[J] >> 31); h0[J] = (h0[J] << 1) | (unsigned)sp;          \
    float spb = (float)((h3[J] >> 4) & 1u);                                             \
    QA2[J] = R_ * (QA2[J] + PA2[J]); PA2[J] = R_ * PA2[J] + (double)sp;                 \
    QB2[J] = RF_ * (QB2[J] + PB2[J]); PB2[J] = RF_ * PB2[J] + spb;                      \
    YO = (float)(C_ * QA2[J]) - (CR100F_ * QB2[J] + C100R100F_ * PB2[J]);               \
  }

// ---------------- fused psp -> spike -> psp scan, NR rows per lane ----------------
// Q = total_rows / NR; lane handles rows r0 + j*Q. Grid = Q/64 blocks x 64.
__global__ __launch_bounds__(64) void psp_spike_psp_scan_kernel(const float* __restrict__ in,
                                                                float* __restrict__ out,
                                                                long Q) {
  const long r0 = (long)blockIdx.x * 64 + threadIdx.x;
  const float* xr[NR];
  float* yr[NR];
#pragma unroll
  for (int j = 0; j < NR; ++j) {
    xr[j] = in + (r0 + j * Q) * TLEN;
    yr[j] = out + (r0 + j * Q) * TLEN;
  }
  double PA1[NR], QA1[NR], PA2[NR], QA2[NR];
  float PB1[NR], QB1[NR], PB2[NR], QB2[NR], ref[NR];
  unsigned h0[NR], h1[NR], h2[NR], h3[NR];
#pragma unroll
  for (int j = 0; j < NR; ++j) {
    PA1[j] = QA1[j] = PA2[j] = QA2[j] = 0.0;
    PB1[j] = QB1[j] = PB2[j] = QB2[j] = 0.f;
    ref[j] = 0.f;
    h0[j] = h1[j] = h2[j] = h3[j] = 0u;
  }
#pragma unroll 1
  for (int tq = 0; tq < 75; ++tq) {
    const int t = 4 * tq;
    float4 xa[NR], xb[NR], yo[NR];
#pragma unroll
    for (int j = 0; j < NR; ++j) {
      xa[j] = *reinterpret_cast<const float4*>(xr[j] + t);
      xb[j] = make_float4(0.f, 0.f, 0.f, 0.f);
      if (t >= 100) xb[j] = *reinterpret_cast<const float4*>(xr[j] + t - 100);
    }
#pragma unroll
    for (int j = 0; j < NR; ++j) PSPSUBJ(j, xa[j].x, xb[j].x, yo[j].x);
#pragma unroll
    for (int j = 0; j < NR; ++j) PSPSUBJ(j, xa[j].y, xb[j].y, yo[j].y);
#pragma unroll
    for (int j = 0; j < NR; ++j) PSPSUBJ(j, xa[j].z, xb[j].z, yo[j].z);
#pragma unroll
    for (int j = 0; j < NR; ++j) PSPSUBJ(j, xa[j].w, xb[j].w, yo[j].w);
#pragma unroll
    for (int j = 0; j < NR; ++j) *reinterpret_cast<float4*>(yr[j] + t) = yo[j];
  }
}

// ---------------- fc1 4-partial reduce + spike + delay3 + psp, NR rows/lane ----------
#define RSDPSUBJ(J, C0, C1, C2, C3, TT, YO)                                             \
  {                                                                                     \
    const int t = (TT);                                                                 \
    float u = ((C0) + (C1)) + ((C2) + (C3));                                            \
    float v = u + ref[J] - THETA;                                                       \
    float sp = (v >= 0.f) ? 1.f : 0.f;                                                  \
    ref[J] = REF_DECAY * ref[J] - 20.0f * sp;                                           \
    h3[J] = (h3[J] << 1) | (h2[J] >> 31); h2[J] = (h2[J] << 1) | (h1[J] >> 31);         \
    h1[J] = (h1[J] << 1) | (h0[J] >> 31); h0[J] = (h0[J] << 1) | (unsigned)sp;          \
    float src = (float)t - dd;                                                          \
    float fi = floorf(src);                                                             \
    int i0 = (int)fi;                                                                   \
    float w = src - fi;                                                                 \
    float s0 = bit_at(h0[J], h1[J], h2[J], h3[J], t - i0);                              \
    float s1 = bit_at(h0[J], h1[J], h2[J], h3[J], t - i0 - 1);                          \
    float z = s0 * (1.f - w) + s1 * w;                                                  \
    float zb = 0.f;                                                                     \
    if (t >= 100) {                                                                     \
      float src2 = (float)(t - 100) - dd;                                               \
      float fi2 = floorf(src2);                                                         \
      int i02 = (int)fi2;                                                               \
      float w2 = src2 - fi2;                                                            \
      float s0b = bit_at(h0[J], h1[J], h2[J], h3[J], t - i02);                          \
      float s1b = bit_at(h0[J], h1[J], h2[J], h3[J], t - i02 - 1);                      \
      zb = s0b * (1.f - w2) + s1b * w2;                                                 \
    }                                                                                   \
    QA[J] = R_ * (QA[J] + PA[J]); PA[J] = R_ * PA[J] + (double)z;                       \
    QB[J] = RF_ * (QB[J] + PB[J]); PB[J] = RF_ * PB[J] + zb;                            \
    YO = (float)(C_ * QA[J]) - (CR100F_ * QB[J] + C100R100F_ * PB[J]);                  \
  }

__global__ __launch_bounds__(64) void reduce_spike_delay_psp_scan_kernel(
    const float* __restrict__ part, const float* __restrict__ dly,
    float* __restrict__ out) {
  const long r0 = (long)blockIdx.x * 64 + threadIdx.x;  // 0..511 (channel)
  const float* p[NR];
  float* yr[NR];
#pragma unroll
  for (int j = 0; j < NR; ++j) {  // rows r0 + j*512 share channel r0
    p[j] = part + (r0 + j * 512) * TLEN;
    yr[j] = out + (r0 + j * 512) * TLEN;
  }
  const float dd = dly[(int)(r0 & 511)];
  double PA[NR], QA[NR];
  float PB[NR], QB[NR], ref[NR];
  unsigned h0[NR], h1[NR], h2[NR], h3[NR];
#pragma unroll
  for (int j = 0; j < NR; ++j) {
    PA[j] = QA[j] = 0.0;
    PB[j] = QB[j] = 0.f;
    ref[j] = 0.f;
    h0[j] = h1[j] = h2[j] = h3[j] = 0u;
  }
#pragma unroll 1
  for (int tq = 0; tq < 75; ++tq) {
    const int t4 = 4 * tq;
    float4 v0[NR], v1[NR], v2[NR], v3[NR], yo[NR];
#pragma unroll
    for (int j = 0; j < NR; ++j) {
      v0[j] = *reinterpret_cast<const float4*>(p[j] + t4);
      v1[j] = *reinterpret_cast<const float4*>(p[j] + 614400 + t4);
      v2[j] = *reinterpret_cast<const float4*>(p[j] + 1228800 + t4);
      v3[j] = *reinterpret_cast<const float4*>(p[j] + 1843200 + t4);
    }
#pragma unroll
    for (int j = 0; j < NR; ++j) RSDPSUBJ(j, v0[j].x, v1[j].x, v2[j].x, v3[j].x, t4 + 0, yo[j].x);
#pragma unroll
    for (int j = 0; j < NR; ++j) RSDPSUBJ(j, v0[j].y, v1[j].y, v2[j].y, v3[j].y, t4 + 1, yo[j].y);
#pragma unroll
    for (int j = 0; j < NR; ++j) RSDPSUBJ(j, v0[j].z, v1[j].z, v2[j].z, v3[j].z, t4 + 2, yo[j].z);
#pragma unroll
    for (int j = 0; j < NR; ++j) RSDPSUBJ(j, v0[j].w, v1[j].w, v2[j].w, v3[j].w, t4 + 3, yo[j].w);
#pragma unroll
    for (int j = 0; j < NR; ++j) *reinterpret_cast<float4*>(yr[j] + t4) = yo[j];
  }
}

// ---------------- 4x4 sum-pool on raw input (float4 over t), scale 0.6875 ----------------
__global__ __launch_bounds__(256) void pool4_kernel(const float* __restrict__ in,
                                                    float* __restrict__ out) {
  int idx = blockIdx.x * 256 + threadIdx.x;  // quad index
  if (idx >= 153600) return;
  int tq = idx % 75;
  int rest = idx / 75;
  int x = rest & 31; rest >>= 5;
  int y = rest & 31; rest >>= 5;  // rest = bc (0..7)
  const float* base = in + ((long)(rest * 128 + y * 4) * 128 + x * 4) * TLEN + tq * 4;
  float4 s = {0.f, 0.f, 0.f, 0.f};
#pragma unroll
  for (int dy = 0; dy < 4; ++dy)
#pragma unroll
    for (int dx = 0; dx < 4; ++dx) {
      float4 v = *reinterpret_cast<const float4*>(base + (dy * 128 + dx) * TLEN);
      s.x += v.x; s.y += v.y; s.z += v.z; s.w += v.w;
    }
  s.x *= 0.6875f; s.y *= 0.6875f; s.z *= 0.6875f; s.w *= 0.6875f;
  *reinterpret_cast<float4*>(out + ((long)(rest * 32 + y) * 32 + x) * TLEN + tq * 4) = s;
}

// ---------------- fused spike scan + 2x2 pool + per-channel delay (round-5 proven) -------
__device__ __forceinline__ int sqz(int r, int q) { return (q & ~7) | ((q + r) & 7); }

__global__ __launch_bounds__(256) void spike_pool2_delay_kernel(const float* __restrict__ u,
                                                                const float* __restrict__ dly,
                                                                float* __restrict__ out,
                                                                int WI, int C) {
  __shared__ float4 ch[64 * 16];            // chunk: 64 rows x 15 quads (60 t), swizzled
  __shared__ unsigned int bits[64 * 13];    // spike bits, stride 13 (odd)
  const int tid = threadIdx.x;
  const long inrow0 = (long)blockIdx.x * 64;
  float ref = 0.f;
  unsigned int wbits = 0;
  for (int cix = 0; cix < 5; ++cix) {
    __syncthreads();
    for (int i = tid; i < 960; i += 256) {
      int r = i / 15, q = i - r * 15;
      ch[r * 16 + sqz(r, q)] = *reinterpret_cast<const float4*>(
          u + (inrow0 + r) * TLEN + cix * 60 + 4 * q);
    }
    __syncthreads();
    if (tid < 64) {
      int r = tid;
#pragma unroll 1
      for (int q = 0; q < 15; ++q) {
        float4 v = ch[r * 16 + sqz(r, q)];
        int t = cix * 60 + 4 * q;
        float x, sp;
        x = v.x + ref - THETA; sp = (x >= 0.f) ? 1.f : 0.f; ref = REF_DECAY * ref - 20.0f * sp;
        wbits |= ((unsigned int)sp) << (t & 31);
        if ((t & 31) == 31) { bits[r * 13 + (t >> 5)] = wbits; wbits = 0; }
        x = v.y + ref - THETA; sp = (x >= 0.f) ? 1.f : 0.f; ref = REF_DECAY * ref - 20.0f * sp;
        wbits |= ((unsigned int)sp) << ((t + 1) & 31);
        if (((t + 1) & 31) == 31) { bits[r * 13 + ((t + 1) >> 5)] = wbits; wbits = 0; }
        x = v.z + ref - THETA; sp = (x >= 0.f) ? 1.f : 0.f; ref = REF_DECAY * ref - 20.0f * sp;
        wbits |= ((unsigned int)sp) << ((t + 2) & 31);
        if (((t + 2) & 31) == 31) { bits[r * 13 + ((t + 2) >> 5)] = wbits; wbits = 0; }
        x = v.w + ref - THETA; sp = (x >= 0.f) ? 1.f : 0.f; ref = REF_DECAY * ref - 20.0f * sp;
        wbits |= ((unsigned int)sp) << ((t + 3) & 31);
        if (((t + 3) & 31) == 31) { bits[r * 13 + ((t + 3) >> 5)] = wbits; wbits = 0; }
      }
    }
  }
  if (tid < 64) bits[tid * 13 + 9] = wbits;  // final partial word (t=288..299)
  __syncthreads();
  const int WO = WI >> 1;
  const int bc = (int)(inrow0 / (WI * WI));
  const int y0 = (int)((inrow0 % (WI * WI)) / WI);
  const float dd = dly[bc % C];
  const long orow0 = (long)bc * (WO * WO) + (y0 >> 1) * WO;
  for (int i = tid; i < 4800; i += 256) {
    int ro = i / TLEN, t = i - ro * TLEN;
    int Yr = ro / WO, X = ro - Yr * WO;
    int ir = (2 * Yr) * WI + 2 * X;
    float src = (float)t - dd;
    float fi = floorf(src);
    int i0 = (int)fi;
    float wf = src - fi;
    bool ok0 = (i0 >= 0) && (i0 < TLEN);
    bool ok1 = (i0 + 1 >= 0) && (i0 + 1 < TLEN);
    int j0 = min(max(i0, 0), TLEN - 1);
    int j1 = min(max(i0 + 1, 0), TLEN - 1);
    int s0i = 0, s1i = 0;
#pragma unroll
    for (int dy = 0; dy < 2; ++dy)
#pragma unroll
      for (int dx = 0; dx < 2; ++dx) {
        int rr = ir + dy * WI + dx;
        s0i += (int)((bits[rr * 13 + (j0 >> 5)] >> (j0 & 31)) & 1u);
        s1i += (int)((bits[rr * 13 + (j1 >> 5)] >> (j1 & 31)) & 1u);
      }
    float s0 = ok0 ? (float)s0i : 0.f;
    float s1 = ok1 ? (float)s1i : 0.f;
    out[(orow0 + ro) * TLEN + t] = (s0 * (1.f - wf) + s1 * wf) * 2.75f;
  }
}

// ---------------- conv1: 2->16 ch, 5x5, pad 2, 32x32, float4 staging ----------------
__global__ __launch_bounds__(256) void conv1_kernel(const float* __restrict__ in,
                                                    const float* __restrict__ w,
                                                    float* __restrict__ out) {
  __shared__ float xl[11520];  // [c2][dy5][x36][t32]
  const int tid = threadIdx.x;
  const int t0 = blockIdx.x * 32;
  const int y = blockIdx.y;
  const int b = blockIdx.z;
  for (int i = tid; i < 2880; i += 256) {
    int tq = i & 7;
    int rest = i >> 3;
    int xp = rest % 36;
    int r2 = rest / 36;
    int dy = r2 % 5;
    int c = r2 / 5;
    int yy = y + dy - 2, xx = xp - 2, t = t0 + tq * 4;
    float4 v = {0.f, 0.f, 0.f, 0.f};
    if (yy >= 0 && yy < 32 && xx >= 0 && xx < 32 && t < TLEN)
      v = *reinterpret_cast<const float4*>(
          in + ((long)((b * 2 + c) * 32 + yy) * 32 + xx) * TLEN + t);
    *reinterpret_cast<float4*>(&xl[rest * 32 + tq * 4]) = v;
  }
  __syncthreads();
  const int tg = tid & 7;
  const int x = tid >> 3;
  float acc[16][4];
#pragma unroll
  for (int o = 0; o < 16; ++o) { acc[o][0] = acc[o][1] = acc[o][2] = acc[o][3] = 0.f; }
  for (int c = 0; c < 2; ++c)
#pragma unroll
    for (int dy = 0; dy < 5; ++dy)
#pragma unroll
      for (int kx = 0; kx < 5; ++kx) {
        const float4 xv = *reinterpret_cast<const float4*>(
            &xl[((c * 5 + dy) * 36 + x + kx) * 32 + tg * 4]);
        const float* wp = w + (c * 5 + dy) * 5 + kx;
#pragma unroll
        for (int o = 0; o < 16; ++o) {
          float wsc = wp[o * 50];
          acc[o][0] += wsc * xv.x; acc[o][1] += wsc * xv.y;
          acc[o][2] += wsc * xv.z; acc[o][3] += wsc * xv.w;
        }
      }
  const int t = t0 + tg * 4;
  if (t < TLEN) {
#pragma unroll
    for (int o = 0; o < 16; ++o) {
      float4 res; res.x = acc[o][0]; res.y = acc[o][1]; res.z = acc[o][2]; res.w = acc[o][3];
      *reinterpret_cast<float4*>(&out[((long)((b * 16 + o) * 32 + y) * 32 + x) * TLEN + t]) = res;
    }
  }
}

// ---------------- conv2: 16->32 ch, 3x3, pad 1, 16x16, float4 staging ----------------
__global__ __launch_bounds__(256) void conv2_kernel(const float* __restrict__ in,
                                                    const float* __restrict__ w,
                                                    float* __restrict__ out) {
  __shared__ float xl[13824];  // [c16][dy3][x18][t16]
  const int tid = threadIdx.x;
  const int t0 = blockIdx.x * 16;
  const int y = blockIdx.y;
  const int b = blockIdx.z;
  for (int i = tid; i < 3456; i += 256) {
    int tq = i & 3;
    int rest = i >> 2;
    int xp = rest % 18;
    int r2 = rest / 18;
    int dy = r2 % 3;
    int c = r2 / 3;
    int yy = y + dy - 1, xx = xp - 1, t = t0 + tq * 4;
    float4 v = {0.f, 0.f, 0.f, 0.f};
    if (yy >= 0 && yy < 16 && xx >= 0 && xx < 16 && t < TLEN)
      v = *reinterpret_cast<const float4*>(
          in + ((long)((b * 16 + c) * 16 + yy) * 16 + xx) * TLEN + t);
    *reinterpret_cast<float4*>(&xl[rest * 16 + tq * 4]) = v;
  }
  __syncthreads();
  const int tg = tid & 3;
  const int x = (tid >> 2) & 15;
  const int oh = tid >> 6;
  float acc[8][4];
#pragma unroll
  for (int o = 0; o < 8; ++o) { acc[o][0] = acc[o][1] = acc[o][2] = acc[o][3] = 0.f; }
  for (int c = 0; c < 16; ++c)
#pragma unroll
    for (int dy = 0; dy < 3; ++dy)
#pragma unroll
      for (int kx = 0; kx < 3; ++kx) {
        const float4 xv = *reinterpret_cast<const float4*>(
            &xl[((c * 3 + dy) * 18 + x + kx) * 16 + tg * 4]);
        const float* wp = w + (c * 3 + dy) * 3 + kx;
#pragma unroll
        for (int oo = 0; oo < 8; ++oo) {
          float wsc = wp[(oh * 8 + oo) * 144];
          acc[oo][0] += wsc * xv.x; acc[oo][1] += wsc * xv.y;
          acc[oo][2] += wsc * xv.z; acc[oo][3] += wsc * xv.w;
        }
      }
  const int t = t0 + tg * 4;
  if (t < TLEN) {
#pragma unroll
    for (int oo = 0; oo < 8; ++oo) {
      int o = oh * 8 + oo;
      float4 res; res.x = acc[oo][0]; res.y = acc[oo][1]; res.z = acc[oo][2]; res.w = acc[oo][3];
      *reinterpret_cast<float4*>(&out[((long)((b * 32 + o) * 16 + y) * 16 + x) * TLEN + t]) = res;
    }
  }
}

// ---------------- fc1: k-split x4, 64x64 tiles, float4 staging, partials out ----------------
__global__ __launch_bounds__(256) void fc1_kernel(const float* __restrict__ x,
                                                  const float* __restrict__ w,
                                                  float* __restrict__ part) {
  __shared__ float wl[64][44];
  __shared__ float xlb[32][68];
  const int tid = threadIdx.x;
  const int t0 = blockIdx.x * 64;
  const int o0 = blockIdx.y * 64;
  const int b = blockIdx.z >> 2;
  const int split = blockIdx.z & 3;
  const int tx = tid & 15, ty = tid >> 4;
  float acc[4][4];
#pragma unroll
  for (int i = 0; i < 4; ++i)
#pragma unroll
    for (int j = 0; j < 4; ++j) acc[i][j] = 0.f;
  const int kbeg = split * 512;
  for (int kc = kbeg; kc < kbeg + 512; kc += 32) {
    __syncthreads();
#pragma unroll
    for (int rr = 0; rr < 2; ++rr) {
      int i = rr * 256 + tid;
      int ol = i >> 3, kq = i & 7;
      float4 v = *reinterpret_cast<const float4*>(w + (long)(o0 + ol) * 2048 + kc + kq * 4);
      *reinterpret_cast<float4*>(&wl[ol][kq * 4]) = v;
    }
#pragma unroll
    for (int rr = 0; rr < 2; ++rr) {
      int i = rr * 256 + tid;
      int kl = i >> 4, tq = i & 15;
      int t = t0 + tq * 4;
      float4 v = {0.f, 0.f, 0.f, 0.f};
      if (t < TLEN)
        v = *reinterpret_cast<const float4*>(x + ((long)b * 2048 + kc + kl) * TLEN + t);
      *reinterpret_cast<float4*>(&xlb[kl][tq * 4]) = v;
    }
    __syncthreads();
#pragma unroll
    for (int k4 = 0; k4 < 8; ++k4) {
      float4 wq[4], xq[4];
#pragma unroll
      for (int i = 0; i < 4; ++i)
        wq[i] = *reinterpret_cast<const float4*>(&wl[ty * 4 + i][k4 * 4]);
#pragma unroll
      for (int j = 0; j < 4; ++j)
        xq[j] = *reinterpret_cast<const float4*>(&xlb[k4 * 4 + j][tx * 4]);
#pragma unroll
      for (int i = 0; i < 4; ++i) {
        float wa[4] = {wq[i].x, wq[i].y, wq[i].z, wq[i].w};
#pragma unroll
        for (int j = 0; j < 4; ++j) {
          float xa[4] = {xq[j].x, xq[j].y, xq[j].z, xq[j].w};
          acc[i][0] += wa[j] * xa[0]; acc[i][1] += wa[j] * xa[1];
          acc[i][2] += wa[j] * xa[2]; acc[i][3] += wa[j] * xa[3];
        }
      }
    }
  }
  const int t = t0 + tx * 4;
  if (t < TLEN) {
#pragma unroll
    for (int i = 0; i < 4; ++i) {
      float4 res; res.x = acc[i][0]; res.y = acc[i][1]; res.z = acc[i][2]; res.w = acc[i][3];
      *reinterpret_cast<float4*>(
          part + ((long)(split * 4 + b) * 512 + o0 + ty * 4 + i) * TLEN + t) = res;
    }
  }
}

// ---------------- fc2 + final spike scan fused, writes d_out ----------------
__global__ __launch_bounds__(320) void fc2_spike_kernel(const float* __restrict__ x,
                                                        const float* __restrict__ w,
                                                        float* __restrict__ out) {
  __shared__ float ul[304];
  int blk = blockIdx.x;
  int b = blk / 11, o = blk % 11;
  int t = threadIdx.x;
  if (t < TLEN) {
    const float* xr = x + (long)b * 512 * TLEN + t;
    const float* wr = w + o * 512;
    float a0 = 0.f, a1 = 0.f, a2 = 0.f, a3 = 0.f;
#pragma unroll 4
    for (int i = 0; i < 512; i += 4) {
      a0 += wr[i] * xr[(long)i * TLEN];
      a1 += wr[i + 1] * xr[(long)(i + 1) * TLEN];
      a2 += wr[i + 2] * xr[(long)(i + 2) * TLEN];
      a3 += wr[i + 3] * xr[(long)(i + 3) * TLEN];
    }
    ul[t] = (a0 + a1) + (a2 + a3);
  }
  __syncthreads();
  if (t == 0) {
    float ref = 0.f;
#pragma unroll 4
    for (int c = 0; c < TLEN; ++c) {
      float v = ul[c] + ref - THETA;
      float sp = (v >= 0.f) ? 1.f : 0.f;
      ul[c] = sp;
      ref = REF_DECAY * ref - 20.0f * sp;
    }
  }
  __syncthreads();
  if (t < TLEN) out[((long)b * 11 + o) * TLEN + t] = ul[t];
}

extern "C" void kernel_launch(void* const* d_in, const int* in_sizes, int n_in,
                              void* d_out, int out_size, void* d_ws, size_t ws_size,
                              hipStream_t stream) {
  const float* input = (const float*)d_in[0];
  const float* w1    = (const float*)d_in[1];
  const float* w2    = (const float*)d_in[2];
  const float* wfc1  = (const float*)d_in[3];
  const float* wfc2  = (const float*)d_in[4];
  const float* d1    = (const float*)d_in[5];
  const float* d2    = (const float*)d_in[6];
  const float* d3    = (const float*)d_in[7];

  float* ws   = (float*)d_ws;
  float* big0 = ws;                    // conv u (19.66M) / fc1 partials (2.46M)
  float* medA = big0 + 19660800;
  float* medB = medA + 4915200;
  float* fcA  = medB + 4915200;
  float* fcB  = fcA + 614400;

  // L1: pool4 -> medA; fused psp->spike->psp scan (4 rows/lane) -> medB = psp(S0)
  hipLaunchKernelGGL(pool4_kernel, dim3(600), dim3(256), 0, stream, input, medA);
  hipLaunchKernelGGL(psp_spike_psp_scan_kernel, dim3(32), dim3(64), 0, stream,
                     medA, medB, 2048L);
  // L2: conv1 -> u1 (big0); fused spike+pool2+delay1 -> medA
  hipLaunchKernelGGL(conv1_kernel, dim3(10, 32, 4), dim3(256), 0, stream, medB, w1, big0);
  hipLaunchKernelGGL(spike_pool2_delay_kernel, dim3(1024), dim3(256), 0, stream,
                     big0, d1, medA, 32, 16);
  // L3: fused psp->spike->psp scan -> medB = psp(S2)
  hipLaunchKernelGGL(psp_spike_psp_scan_kernel, dim3(64), dim3(64), 0, stream,
                     medA, medB, 4096L);
  // L4: conv2 -> u3 (big0); fused spike+pool2+delay2 -> medA
  hipLaunchKernelGGL(conv2_kernel, dim3(19, 16, 4), dim3(256), 0, stream, medB, w2, big0);
  hipLaunchKernelGGL(spike_pool2_delay_kernel, dim3(512), dim3(256), 0, stream,
                     big0, d2, medA, 16, 32);
  // L5: fused psp->spike->psp scan -> medB = psp(S4)
  hipLaunchKernelGGL(psp_spike_psp_scan_kernel, dim3(32), dim3(64), 0, stream,
                     medA, medB, 2048L);
  // L6+L7 head: fc1 -> partials (big0); fused reduce+spike+delay3+psp (4 rows/lane) -> fcB
  hipLaunchKernelGGL(fc1_kernel, dim3(5, 8, 16), dim3(256), 0, stream, medB, wfc1, big0);
  hipLaunchKernelGGL(reduce_spike_delay_psp_scan_kernel, dim3(8), dim3(64), 0, stream,
                     big0, d3, fcB);
  // L7: fc2 + final spike -> d_out
  hipLaunchKernelGGL(fc2_spike_kernel, dim3(44), dim3(320), 0, stream, fcB, wfc2, (float*)d_out);
}

// Round 15
// 443.188 us; speedup vs baseline: 2.2957x; 2.2957x over previous
//
#include <hip/hip_runtime.h>

#define TLEN 300
#define THETA 10.0f
#define REF_DECAY 0.36787944117144233f

// Alpha-kernel recurrence constants: eps[k] = C*k*R^k truncated at k<100.
// y[t] = C*QA[t] - C*R^100*QB[t] - 100*C*R^100*PB[t]; (PA,QA) on x[t], (PB,QB) on x[t-100]:
// P[t] = R*P[t-1] + x[t];  Q[t] = R*(Q[t-1] + P[t-1]).
// A-system in double (main term); B-system in float (contribution scaled by R^100=4.5e-5).
#define R_ 0.9048374180359595732
#define C_ 0.2718281828459045235
#define R100_ 4.5399929762484852e-05
#define RF_ ((float)R_)
#define CR100F_ ((float)(C_ * R100_))
#define C100R100F_ ((float)(100.0 * C_ * R100_))

// ---------------- eps table (for fir_direct): eps[k] = (k/10)exp(1-k/10) ----------------
__global__ void eps_init_kernel(float* __restrict__ eps) {
  int k = threadIdx.x;
  if (k < 104) eps[k] = 0.f;
  if (k < 100) {
    float a = (float)k / 10.0f;
    eps[k] = a * expf(1.0f - a);
  }
}

// ---------------- fused psp -> spike -> psp scan, one row per lane ----------------
#define PSPSUB(XA, XB, YO)                                                              \
  {                                                                                     \
    QA1 = R_ * (QA1 + PA1); PA1 = R_ * PA1 + (double)(XA);                              \
    QB1 = RF_ * (QB1 + PB1); PB1 = RF_ * PB1 + (XB);                                    \
    float u = (float)(C_ * QA1) - (CR100F_ * QB1 + C100R100F_ * PB1);                   \
    float v = u + ref - THETA;                                                          \
    float sp = (v >= 0.f) ? 1.f : 0.f;                                                  \
    ref = REF_DECAY * ref - 20.0f * sp;                                                 \
    h3 = (h3 << 1) | (h2 >> 31); h2 = (h2 << 1) | (h1 >> 31);                           \
    h1 = (h1 << 1) | (h0 >> 31); h0 = (h0 << 1) | (unsigned)sp;                         \
    float spb = (float)((h3 >> 4) & 1u);                                                \
    QA2 = R_ * (QA2 + PA2); PA2 = R_ * PA2 + (double)sp;                                \
    QB2 = RF_ * (QB2 + PB2); PB2 = RF_ * PB2 + spb;                                     \
    YO = (float)(C_ * QA2) - (CR100F_ * QB2 + C100R100F_ * PB2);                        \
  }

__global__ __launch_bounds__(64) void psp_spike_psp_scan_kernel(const float* __restrict__ in,
                                                                float* __restrict__ out,
                                                                long rows) {
  long row = (long)blockIdx.x * 64 + threadIdx.x;
  if (row >= rows) return;
  const float* xr = in + row * TLEN;
  float* yr = out + row * TLEN;
  double PA1 = 0, QA1 = 0, PA2 = 0, QA2 = 0;
  float PB1 = 0.f, QB1 = 0.f, PB2 = 0.f, QB2 = 0.f;
  float ref = 0.f;
  unsigned h0 = 0, h1 = 0, h2 = 0, h3 = 0;
#pragma unroll 1
  for (int tq = 0; tq < 75; ++tq) {
    const int t = 4 * tq;
    const float4 xa = *reinterpret_cast<const float4*>(xr + t);
    float4 xb = make_float4(0.f, 0.f, 0.f, 0.f);
    if (t >= 100) xb = *reinterpret_cast<const float4*>(xr + t - 100);
    float4 yo;
    PSPSUB(xa.x, xb.x, yo.x);
    PSPSUB(xa.y, xb.y, yo.y);
    PSPSUB(xa.z, xb.z, yo.z);
    PSPSUB(xa.w, xb.w, yo.w);
    *reinterpret_cast<float4*>(yr + t) = yo;
  }
}

// ---------------- 4x4 sum-pool on raw input (float4 over t), scale 0.6875 ----------------
__global__ __launch_bounds__(256) void pool4_kernel(const float* __restrict__ in,
                                                    float* __restrict__ out) {
  int idx = blockIdx.x * 256 + threadIdx.x;  // quad index
  if (idx >= 153600) return;
  int tq = idx % 75;
  int rest = idx / 75;
  int x = rest & 31; rest >>= 5;
  int y = rest & 31; rest >>= 5;  // rest = bc (0..7)
  const float* base = in + ((long)(rest * 128 + y * 4) * 128 + x * 4) * TLEN + tq * 4;
  float4 s = {0.f, 0.f, 0.f, 0.f};
#pragma unroll
  for (int dy = 0; dy < 4; ++dy)
#pragma unroll
    for (int dx = 0; dx < 4; ++dx) {
      float4 v = *reinterpret_cast<const float4*>(base + (dy * 128 + dx) * TLEN);
      s.x += v.x; s.y += v.y; s.z += v.z; s.w += v.w;
    }
  s.x *= 0.6875f; s.y *= 0.6875f; s.z *= 0.6875f; s.w *= 0.6875f;
  *reinterpret_cast<float4*>(out + ((long)(rest * 32 + y) * 32 + x) * TLEN + tq * 4) = s;
}

// 4-tap x 8-output FMA block; statement order identical to prior verified rounds.
#define FIRSTEP(e, A, B, C)                                                              \
  acc[0] += e.x * B.x; acc[1] += e.x * B.y; acc[2] += e.x * B.z; acc[3] += e.x * B.w;    \
  acc[4] += e.x * C.x; acc[5] += e.x * C.y; acc[6] += e.x * C.z; acc[7] += e.x * C.w;    \
  acc[0] += e.y * A.w; acc[1] += e.y * B.x; acc[2] += e.y * B.y; acc[3] += e.y * B.z;    \
  acc[4] += e.y * B.w; acc[5] += e.y * C.x; acc[6] += e.y * C.y; acc[7] += e.y * C.z;    \
  acc[0] += e.z * A.z; acc[1] += e.z * A.w; acc[2] += e.z * B.x; acc[3] += e.z * B.y;    \
  acc[4] += e.z * B.z; acc[5] += e.z * B.w; acc[6] += e.z * C.x; acc[7] += e.z * C.y;    \
  acc[0] += e.w * A.y; acc[1] += e.w * A.z; acc[2] += e.w * A.w; acc[3] += e.w * B.x;    \
  acc[4] += e.w * B.y; acc[5] += e.w * B.z; acc[6] += e.w * B.w; acc[7] += e.w * C.x;

__device__ __forceinline__ float4 ldq(const float* __restrict__ rowp, int w) {
  if (w >= 0 && w < TLEN) return *reinterpret_cast<const float4*>(rowp + w);
  return make_float4(0.f, 0.f, 0.f, 0.f);
}

// ---------------- direct-from-global 100-tap FIR (L7 psp), 8 outputs/thread ----------
__global__ __launch_bounds__(256) void fir_direct_kernel(const float* __restrict__ in,
                                                         float* __restrict__ out,
                                                         const float* __restrict__ epsg,
                                                         int rows) {
  int task = blockIdx.x * 256 + threadIdx.x;
  int row = task / 38;
  int l = task - row * 38;
  if (row >= rows) return;
  const float* rowp = in + (long)row * TLEN;
  const int t0 = 8 * l;
  float4 A = ldq(rowp, t0 - 4);
  float4 B = ldq(rowp, t0);
  float4 C = ldq(rowp, t0 + 4);
  float acc[8];
#pragma unroll
  for (int j = 0; j < 8; ++j) acc[j] = 0.f;
#pragma unroll 1
  for (int kg0 = 0; kg0 < 80; kg0 += 20) {
    const float* ep = epsg + kg0;
#pragma unroll
    for (int kk = 0; kk < 5; ++kk) {
      const float4 e = *reinterpret_cast<const float4*>(ep + 4 * kk);
      const int kg = kg0 + 4 * kk;
      FIRSTEP(e, A, B, C);
      C = B; B = A;
      A = ldq(rowp, t0 - kg - 8);
    }
    __builtin_amdgcn_sched_barrier(0);
  }
#pragma unroll
  for (int kk = 0; kk < 5; ++kk) {
    const float4 e = *reinterpret_cast<const float4*>(epsg + 80 + 4 * kk);
    FIRSTEP(e, A, B, C);
    C = B; B = A;
    if (kk < 4) A = ldq(rowp, t0 - 88 - 4 * kk);
  }
  float* op = out + (long)row * TLEN + t0;
  *reinterpret_cast<float4*>(op) = make_float4(acc[0], acc[1], acc[2], acc[3]);
  if (t0 + 4 < TLEN)
    *reinterpret_cast<float4*>(op + 4) = make_float4(acc[4], acc[5], acc[6], acc[7]);
}

// ---------------- fc1 4-partial sum + scan -> spikes S5 ----------------
__global__ __launch_bounds__(64) void scan_reduce4_kernel(const float* __restrict__ part,
                                                          float* __restrict__ s) {
  long row = (long)blockIdx.x * 64 + threadIdx.x;  // 2048 rows
  const float* p = part + row * TLEN;
  float* o = s + row * TLEN;
  float ref = 0.f;
#pragma unroll 4
  for (int c4 = 0; c4 < 75; ++c4) {
    const float4 v0 = *reinterpret_cast<const float4*>(p + 4 * c4);
    const float4 v1 = *reinterpret_cast<const float4*>(p + 614400 + 4 * c4);
    const float4 v2 = *reinterpret_cast<const float4*>(p + 1228800 + 4 * c4);
    const float4 v3 = *reinterpret_cast<const float4*>(p + 1843200 + 4 * c4);
    float4 u4;
    u4.x = (v0.x + v1.x) + (v2.x + v3.x);
    u4.y = (v0.y + v1.y) + (v2.y + v3.y);
    u4.z = (v0.z + v1.z) + (v2.z + v3.z);
    u4.w = (v0.w + v1.w) + (v2.w + v3.w);
    float v, sp;
    v = u4.x + ref - THETA; sp = (v >= 0.f) ? 1.f : 0.f; u4.x = sp; ref = REF_DECAY * ref - 20.0f * sp;
    v = u4.y + ref - THETA; sp = (v >= 0.f) ? 1.f : 0.f; u4.y = sp; ref = REF_DECAY * ref - 20.0f * sp;
    v = u4.z + ref - THETA; sp = (v >= 0.f) ? 1.f : 0.f; u4.z = sp; ref = REF_DECAY * ref - 20.0f * sp;
    v = u4.w + ref - THETA; sp = (v >= 0.f) ? 1.f : 0.f; u4.w = sp; ref = REF_DECAY * ref - 20.0f * sp;
    *reinterpret_cast<float4*>(o + 4 * c4) = u4;
  }
}

// ---------------- per-channel delay (lerp gather), C=512, S=1 ----------------
__global__ __launch_bounds__(256) void delay_kernel(const float* __restrict__ in,
                                                    const float* __restrict__ d,
                                                    float* __restrict__ out, int total) {
  int idx = blockIdx.x * 256 + threadIdx.x;
  if (idx >= total) return;
  int t = idx % TLEN;
  int rest = idx / TLEN;  // row = b*512 + c
  float dd = d[rest & 511];
  float src = (float)t - dd;
  float fi = floorf(src);
  int i0 = (int)fi;
  float wf = src - fi;
  const float* base = in + (long)rest * TLEN;
  float v0 = (i0 >= 0 && i0 < TLEN) ? base[min(max(i0, 0), TLEN - 1)] : 0.f;
  float v1 = (i0 + 1 >= 0 && i0 + 1 < TLEN) ? base[min(max(i0 + 1, 0), TLEN - 1)] : 0.f;
  out[idx] = v0 * (1.f - wf) + v1 * wf;
}

// ---------------- fused spike scan + 2x2 pool + per-channel delay (round-5 proven) -------
__device__ __forceinline__ int sqz(int r, int q) { return (q & ~7) | ((q + r) & 7); }

__global__ __launch_bounds__(256) void spike_pool2_delay_kernel(const float* __restrict__ u,
                                                                const float* __restrict__ dly,
                                                                float* __restrict__ out,
                                                                int WI, int C) {
  __shared__ float4 ch[64 * 16];            // chunk: 64 rows x 15 quads (60 t), swizzled
  __shared__ unsigned int bits[64 * 13];    // spike bits, stride 13 (odd)
  const int tid = threadIdx.x;
  const long inrow0 = (long)blockIdx.x * 64;
  float ref = 0.f;
  unsigned int wbits = 0;
  for (int cix = 0; cix < 5; ++cix) {
    __syncthreads();
    for (int i = tid; i < 960; i += 256) {
      int r = i / 15, q = i - r * 15;
      ch[r * 16 + sqz(r, q)] = *reinterpret_cast<const float4*>(
          u + (inrow0 + r) * TLEN + cix * 60 + 4 * q);
    }
    __syncthreads();
    if (tid < 64) {
      int r = tid;
#pragma unroll 1
      for (int q = 0; q < 15; ++q) {
        float4 v = ch[r * 16 + sqz(r, q)];
        int t = cix * 60 + 4 * q;
        float x, sp;
        x = v.x + ref - THETA; sp = (x >= 0.f) ? 1.f : 0.f; ref = REF_DECAY * ref - 20.0f * sp;
        wbits |= ((unsigned int)sp) << (t & 31);
        if ((t & 31) == 31) { bits[r * 13 + (t >> 5)] = wbits; wbits = 0; }
        x = v.y + ref - THETA; sp = (x >= 0.f) ? 1.f : 0.f; ref = REF_DECAY * ref - 20.0f * sp;
        wbits |= ((unsigned int)sp) << ((t + 1) & 31);
        if (((t + 1) & 31) == 31) { bits[r * 13 + ((t + 1) >> 5)] = wbits; wbits = 0; }
        x = v.z + ref - THETA; sp = (x >= 0.f) ? 1.f : 0.f; ref = REF_DECAY * ref - 20.0f * sp;
        wbits |= ((unsigned int)sp) << ((t + 2) & 31);
        if (((t + 2) & 31) == 31) { bits[r * 13 + ((t + 2) >> 5)] = wbits; wbits = 0; }
        x = v.w + ref - THETA; sp = (x >= 0.f) ? 1.f : 0.f; ref = REF_DECAY * ref - 20.0f * sp;
        wbits |= ((unsigned int)sp) << ((t + 3) & 31);
        if (((t + 3) & 31) == 31) { bits[r * 13 + ((t + 3) >> 5)] = wbits; wbits = 0; }
      }
    }
  }
  if (tid < 64) bits[tid * 13 + 9] = wbits;  // final partial word (t=288..299)
  __syncthreads();
  const int WO = WI >> 1;
  const int bc = (int)(inrow0 / (WI * WI));
  const int y0 = (int)((inrow0 % (WI * WI)) / WI);
  const float dd = dly[bc % C];
  const long orow0 = (long)bc * (WO * WO) + (y0 >> 1) * WO;
  for (int i = tid; i < 4800; i += 256) {
    int ro = i / TLEN, t = i - ro * TLEN;
    int Yr = ro / WO, X = ro - Yr * WO;
    int ir = (2 * Yr) * WI + 2 * X;
    float src = (float)t - dd;
    float fi = floorf(src);
    int i0 = (int)fi;
    float wf = src - fi;
    bool ok0 = (i0 >= 0) && (i0 < TLEN);
    bool ok1 = (i0 + 1 >= 0) && (i0 + 1 < TLEN);
    int j0 = min(max(i0, 0), TLEN - 1);
    int j1 = min(max(i0 + 1, 0), TLEN - 1);
    int s0i = 0, s1i = 0;
#pragma unroll
    for (int dy = 0; dy < 2; ++dy)
#pragma unroll
      for (int dx = 0; dx < 2; ++dx) {
        int rr = ir + dy * WI + dx;
        s0i += (int)((bits[rr * 13 + (j0 >> 5)] >> (j0 & 31)) & 1u);
        s1i += (int)((bits[rr * 13 + (j1 >> 5)] >> (j1 & 31)) & 1u);
      }
    float s0 = ok0 ? (float)s0i : 0.f;
    float s1 = ok1 ? (float)s1i : 0.f;
    out[(orow0 + ro) * TLEN + t] = (s0 * (1.f - wf) + s1 * wf) * 2.75f;
  }
}

// ---------------- conv1: 2->16 ch, 5x5, pad 2, 32x32, float4 staging ----------------
__global__ __launch_bounds__(256) void conv1_kernel(const float* __restrict__ in,
                                                    const float* __restrict__ w,
                                                    float* __restrict__ out) {
  __shared__ float xl[11520];  // [c2][dy5][x36][t32]
  const int tid = threadIdx.x;
  const int t0 = blockIdx.x * 32;
  const int y = blockIdx.y;
  const int b = blockIdx.z;
  for (int i = tid; i < 2880; i += 256) {
    int tq = i & 7;
    int rest = i >> 3;
    int xp = rest % 36;
    int r2 = rest / 36;
    int dy = r2 % 5;
    int c = r2 / 5;
    int yy = y + dy - 2, xx = xp - 2, t = t0 + tq * 4;
    float4 v = {0.f, 0.f, 0.f, 0.f};
    if (yy >= 0 && yy < 32 && xx >= 0 && xx < 32 && t < TLEN)
      v = *reinterpret_cast<const float4*>(
          in + ((long)((b * 2 + c) * 32 + yy) * 32 + xx) * TLEN + t);
    *reinterpret_cast<float4*>(&xl[rest * 32 + tq * 4]) = v;
  }
  __syncthreads();
  const int tg = tid & 7;
  const int x = tid >> 3;
  float acc[16][4];
#pragma unroll
  for (int o = 0; o < 16; ++o) { acc[o][0] = acc[o][1] = acc[o][2] = acc[o][3] = 0.f; }
  for (int c = 0; c < 2; ++c)
#pragma unroll
    for (int dy = 0; dy < 5; ++dy)
#pragma unroll
      for (int kx = 0; kx < 5; ++kx) {
        const float4 xv = *reinterpret_cast<const float4*>(
            &xl[((c * 5 + dy) * 36 + x + kx) * 32 + tg * 4]);
        const float* wp = w + (c * 5 + dy) * 5 + kx;
#pragma unroll
        for (int o = 0; o < 16; ++o) {
          float wsc = wp[o * 50];
          acc[o][0] += wsc * xv.x; acc[o][1] += wsc * xv.y;
          acc[o][2] += wsc * xv.z; acc[o][3] += wsc * xv.w;
        }
      }
  const int t = t0 + tg * 4;
  if (t < TLEN) {
#pragma unroll
    for (int o = 0; o < 16; ++o) {
      float4 res; res.x = acc[o][0]; res.y = acc[o][1]; res.z = acc[o][2]; res.w = acc[o][3];
      *reinterpret_cast<float4*>(&out[((long)((b * 16 + o) * 32 + y) * 32 + x) * TLEN + t]) = res;
    }
  }
}

// ---------------- conv2: 16->32 ch, 3x3, pad 1, 16x16, float4 staging ----------------
__global__ __launch_bounds__(256) void conv2_kernel(const float* __restrict__ in,
                                                    const float* __restrict__ w,
                                                    float* __restrict__ out) {
  __shared__ float xl[13824];  // [c16][dy3][x18][t16]
  const int tid = threadIdx.x;
  const int t0 = blockIdx.x * 16;
  const int y = blockIdx.y;
  const int b = blockIdx.z;
  for (int i = tid; i < 3456; i += 256) {
    int tq = i & 3;
    int rest = i >> 2;
    int xp = rest % 18;
    int r2 = rest / 18;
    int dy = r2 % 3;
    int c = r2 / 3;
    int yy = y + dy - 1, xx = xp - 1, t = t0 + tq * 4;
    float4 v = {0.f, 0.f, 0.f, 0.f};
    if (yy >= 0 && yy < 16 && xx >= 0 && xx < 16 && t < TLEN)
      v = *reinterpret_cast<const float4*>(
          in + ((long)((b * 16 + c) * 16 + yy) * 16 + xx) * TLEN + t);
    *reinterpret_cast<float4*>(&xl[rest * 16 + tq * 4]) = v;
  }
  __syncthreads();
  const int tg = tid & 3;
  const int x = (tid >> 2) & 15;
  const int oh = tid >> 6;
  float acc[8][4];
#pragma unroll
  for (int o = 0; o < 8; ++o) { acc[o][0] = acc[o][1] = acc[o][2] = acc[o][3] = 0.f; }
  for (int c = 0; c < 16; ++c)
#pragma unroll
    for (int dy = 0; dy < 3; ++dy)
#pragma unroll
      for (int kx = 0; kx < 3; ++kx) {
        const float4 xv = *reinterpret_cast<const float4*>(
            &xl[((c * 3 + dy) * 18 + x + kx) * 16 + tg * 4]);
        const float* wp = w + (c * 3 + dy) * 3 + kx;
#pragma unroll
        for (int oo = 0; oo < 8; ++oo) {
          float wsc = wp[(oh * 8 + oo) * 144];
          acc[oo][0] += wsc * xv.x; acc[oo][1] += wsc * xv.y;
          acc[oo][2] += wsc * xv.z; acc[oo][3] += wsc * xv.w;
        }
      }
  const int t = t0 + tg * 4;
  if (t < TLEN) {
#pragma unroll
    for (int oo = 0; oo < 8; ++oo) {
      int o = oh * 8 + oo;
      float4 res; res.x = acc[oo][0]; res.y = acc[oo][1]; res.z = acc[oo][2]; res.w = acc[oo][3];
      *reinterpret_cast<float4*>(&out[((long)((b * 32 + o) * 16 + y) * 16 + x) * TLEN + t]) = res;
    }
  }
}

// ---------------- fc1: k-split x4, 64x64 tiles, float4 staging, partials out ----------------
__global__ __launch_bounds__(256) void fc1_kernel(const float* __restrict__ x,
                                                  const float* __restrict__ w,
                                                  float* __restrict__ part) {
  __shared__ float wl[64][44];
  __shared__ float xlb[32][68];
  const int tid = threadIdx.x;
  const int t0 = blockIdx.x * 64;
  const int o0 = blockIdx.y * 64;
  const int b = blockIdx.z >> 2;
  const int split = blockIdx.z & 3;
  const int tx = tid & 15, ty = tid >> 4;
  float acc[4][4];
#pragma unroll
  for (int i = 0; i < 4; ++i)
#pragma unroll
    for (int j = 0; j < 4; ++j) acc[i][j] = 0.f;
  const int kbeg = split * 512;
  for (int kc = kbeg; kc < kbeg + 512; kc += 32) {
    __syncthreads();
#pragma unroll
    for (int rr = 0; rr < 2; ++rr) {
      int i = rr * 256 + tid;
      int ol = i >> 3, kq = i & 7;
      float4 v = *reinterpret_cast<const float4*>(w + (long)(o0 + ol) * 2048 + kc + kq * 4);
      *reinterpret_cast<float4*>(&wl[ol][kq * 4]) = v;
    }
#pragma unroll
    for (int rr = 0; rr < 2; ++rr) {
      int i = rr * 256 + tid;
      int kl = i >> 4, tq = i & 15;
      int t = t0 + tq * 4;
      float4 v = {0.f, 0.f, 0.f, 0.f};
      if (t < TLEN)
        v = *reinterpret_cast<const float4*>(x + ((long)b * 2048 + kc + kl) * TLEN + t);
      *reinterpret_cast<float4*>(&xlb[kl][tq * 4]) = v;
    }
    __syncthreads();
#pragma unroll
    for (int k4 = 0; k4 < 8; ++k4) {
      float4 wq[4], xq[4];
#pragma unroll
      for (int i = 0; i < 4; ++i)
        wq[i] = *reinterpret_cast<const float4*>(&wl[ty * 4 + i][k4 * 4]);
#pragma unroll
      for (int j = 0; j < 4; ++j)
        xq[j] = *reinterpret_cast<const float4*>(&xlb[k4 * 4 + j][tx * 4]);
#pragma unroll
      for (int i = 0; i < 4; ++i) {
        float wa[4] = {wq[i].x, wq[i].y, wq[i].z, wq[i].w};
#pragma unroll
        for (int j = 0; j < 4; ++j) {
          float xa[4] = {xq[j].x, xq[j].y, xq[j].z, xq[j].w};
          acc[i][0] += wa[j] * xa[0]; acc[i][1] += wa[j] * xa[1];
          acc[i][2] += wa[j] * xa[2]; acc[i][3] += wa[j] * xa[3];
        }
      }
    }
  }
  const int t = t0 + tx * 4;
  if (t < TLEN) {
#pragma unroll
    for (int i = 0; i < 4; ++i) {
      float4 res; res.x = acc[i][0]; res.y = acc[i][1]; res.z = acc[i][2]; res.w = acc[i][3];
      *reinterpret_cast<float4*>(
          part + ((long)(split * 4 + b) * 512 + o0 + ty * 4 + i) * TLEN + t) = res;
    }
  }
}

// ---------------- fc2 + final spike scan fused, writes d_out ----------------
__global__ __launch_bounds__(320) void fc2_spike_kernel(const float* __restrict__ x,
                                                        const float* __restrict__ w,
                                                        float* __restrict__ out) {
  __shared__ float ul[304];
  int blk = blockIdx.x;
  int b = blk / 11, o = blk % 11;
  int t = threadIdx.x;
  if (t < TLEN) {
    const float* xr = x + (long)b * 512 * TLEN + t;
    const float* wr = w + o * 512;
    float a0 = 0.f, a1 = 0.f, a2 = 0.f, a3 = 0.f;
#pragma unroll 4
    for (int i = 0; i < 512; i += 4) {
      a0 += wr[i] * xr[(long)i * TLEN];
      a1 += wr[i + 1] * xr[(long)(i + 1) * TLEN];
      a2 += wr[i + 2] * xr[(long)(i + 2) * TLEN];
      a3 += wr[i + 3] * xr[(long)(i + 3) * TLEN];
    }
    ul[t] = (a0 + a1) + (a2 + a3);
  }
  __syncthreads();
  if (t == 0) {
    float ref = 0.f;
#pragma unroll 4
    for (int c = 0; c < TLEN; ++c) {
      float v = ul[c] + ref - THETA;
      float sp = (v >= 0.f) ? 1.f : 0.f;
      ul[c] = sp;
      ref = REF_DECAY * ref - 20.0f * sp;
    }
  }
  __syncthreads();
  if (t < TLEN) out[((long)b * 11 + o) * TLEN + t] = ul[t];
}

extern "C" void kernel_launch(void* const* d_in, const int* in_sizes, int n_in,
                              void* d_out, int out_size, void* d_ws, size_t ws_size,
                              hipStream_t stream) {
  const float* input = (const float*)d_in[0];
  const float* w1    = (const float*)d_in[1];
  const float* w2    = (const float*)d_in[2];
  const float* wfc1  = (const float*)d_in[3];
  const float* wfc2  = (const float*)d_in[4];
  const float* d1    = (const float*)d_in[5];
  const float* d2    = (const float*)d_in[6];
  const float* d3    = (const float*)d_in[7];

  float* ws   = (float*)d_ws;
  float* big0 = ws;                    // conv u (19.66M) / fc1 partials (2.46M)
  float* medA = big0 + 19660800;
  float* medB = medA + 4915200;
  float* fcA  = medB + 4915200;
  float* fcB  = fcA + 614400;
  float* eps  = fcB + 614400;

  hipLaunchKernelGGL(eps_init_kernel, dim3(1), dim3(128), 0, stream, eps);

  // L1: pool4 -> medA; fused psp->spike->psp scan -> medB = psp(S0)
  hipLaunchKernelGGL(pool4_kernel, dim3(600), dim3(256), 0, stream, input, medA);
  hipLaunchKernelGGL(psp_spike_psp_scan_kernel, dim3(128), dim3(64), 0, stream,
                     medA, medB, 8192L);
  // L2: conv1 -> u1 (big0); fused spike+pool2+delay1 -> medA
  hipLaunchKernelGGL(conv1_kernel, dim3(10, 32, 4), dim3(256), 0, stream, medB, w1, big0);
  hipLaunchKernelGGL(spike_pool2_delay_kernel, dim3(1024), dim3(256), 0, stream,
                     big0, d1, medA, 32, 16);
  // L3: fused psp->spike->psp scan -> medB = psp(S2)
  hipLaunchKernelGGL(psp_spike_psp_scan_kernel, dim3(256), dim3(64), 0, stream,
                     medA, medB, 16384L);
  // L4: conv2 -> u3 (big0); fused spike+pool2+delay2 -> medA
  hipLaunchKernelGGL(conv2_kernel, dim3(19, 16, 4), dim3(256), 0, stream, medB, w2, big0);
  hipLaunchKernelGGL(spike_pool2_delay_kernel, dim3(512), dim3(256), 0, stream,
                     big0, d2, medA, 16, 32);
  // L5: fused psp->spike->psp scan -> medB = psp(S4)
  hipLaunchKernelGGL(psp_spike_psp_scan_kernel, dim3(128), dim3(64), 0, stream,
                     medA, medB, 8192L);
  // L6: fc1 -> partials (big0); sum+scan -> S5 (fcA)
  hipLaunchKernelGGL(fc1_kernel, dim3(5, 8, 16), dim3(256), 0, stream, medB, wfc1, big0);
  hipLaunchKernelGGL(scan_reduce4_kernel, dim3(32), dim3(64), 0, stream, big0, fcA);
  // L7: delay3 -> fcB; psp (FIR) -> fcA; fc2+spike -> d_out
  hipLaunchKernelGGL(delay_kernel, dim3(2400), dim3(256), 0, stream, fcA, d3, fcB, 614400);
  hipLaunchKernelGGL(fir_direct_kernel, dim3(304), dim3(256), 0, stream, fcB, fcA, eps, 2048);
  hipLaunchKernelGGL(fc2_spike_kernel, dim3(44), dim3(320), 0, stream, fcA, wfc2, (float*)d_out);
}

// Round 16
// 441.629 us; speedup vs baseline: 2.3038x; 1.0035x over previous
//
#include <hip/hip_runtime.h>

#define TLEN 300
#define THETA 10.0f
#define REF_DECAY 0.36787944117144233f

// Alpha-kernel recurrence constants: eps[k] = C*k*R^k truncated at k<100.
// y[t] = C*QA[t] - C*R^100*QB[t] - 100*C*R^100*PB[t]; (PA,QA) on x[t], (PB,QB) on x[t-100]:
// P[t] = R*P[t-1] + x[t];  Q[t] = R*(Q[t-1] + P[t-1]).
// A-system in double (main term); B-system in float (contribution scaled by R^100=4.5e-5).
#define R_ 0.9048374180359595732
#define C_ 0.2718281828459045235
#define R100_ 4.5399929762484852e-05
#define RF_ ((float)R_)
#define CR100F_ ((float)(C_ * R100_))
#define C100R100F_ ((float)(100.0 * C_ * R100_))

// ---------------- eps table (for fir_direct): eps[k] = (k/10)exp(1-k/10) ----------------
__global__ void eps_init_kernel(float* __restrict__ eps) {
  int k = threadIdx.x;
  if (k < 104) eps[k] = 0.f;
  if (k < 100) {
    float a = (float)k / 10.0f;
    eps[k] = a * expf(1.0f - a);
  }
}

// ---------------- fused psp -> spike -> psp scan, one row per lane ----------------
#define PSPSUB(XA, XB, YO)                                                              \
  {                                                                                     \
    QA1 = R_ * (QA1 + PA1); PA1 = R_ * PA1 + (double)(XA);                              \
    QB1 = RF_ * (QB1 + PB1); PB1 = RF_ * PB1 + (XB);                                    \
    float u = (float)(C_ * QA1) - (CR100F_ * QB1 + C100R100F_ * PB1);                   \
    float v = u + ref - THETA;                                                          \
    float sp = (v >= 0.f) ? 1.f : 0.f;                                                  \
    ref = REF_DECAY * ref - 20.0f * sp;                                                 \
    h3 = (h3 << 1) | (h2 >> 31); h2 = (h2 << 1) | (h1 >> 31);                           \
    h1 = (h1 << 1) | (h0 >> 31); h0 = (h0 << 1) | (unsigned)sp;                         \
    float spb = (float)((h3 >> 4) & 1u);                                                \
    QA2 = R_ * (QA2 + PA2); PA2 = R_ * PA2 + (double)sp;                                \
    QB2 = RF_ * (QB2 + PB2); PB2 = RF_ * PB2 + spb;                                     \
    YO = (float)(C_ * QA2) - (CR100F_ * QB2 + C100R100F_ * PB2);                        \
  }

// 4-deep prefetch rings for the two load streams (xa at t, xb at t-100):
// loads issued 4 iterations ahead so ~4 requests stay in flight per lane.
__global__ __launch_bounds__(64) void psp_spike_psp_scan_kernel(const float* __restrict__ in,
                                                                float* __restrict__ out,
                                                                long rows) {
  long row = (long)blockIdx.x * 64 + threadIdx.x;
  if (row >= rows) return;
  const float* xr = in + row * TLEN;
  float* yr = out + row * TLEN;
  double PA1 = 0, QA1 = 0, PA2 = 0, QA2 = 0;
  float PB1 = 0.f, QB1 = 0.f, PB2 = 0.f, QB2 = 0.f;
  float ref = 0.f;
  unsigned h0 = 0, h1 = 0, h2 = 0, h3 = 0;
  float4 a0 = *reinterpret_cast<const float4*>(xr);
  float4 a1 = *reinterpret_cast<const float4*>(xr + 4);
  float4 a2 = *reinterpret_cast<const float4*>(xr + 8);
  float4 a3 = *reinterpret_cast<const float4*>(xr + 12);
  const float4 z4 = make_float4(0.f, 0.f, 0.f, 0.f);
  float4 b0 = z4, b1 = z4, b2 = z4, b3 = z4;
#pragma unroll 1
  for (int tq = 0; tq < 75; ++tq) {
    const int t = 4 * tq;
    const float4 xa = a0;
    a0 = a1; a1 = a2; a2 = a3;
    if (tq < 71) a3 = *reinterpret_cast<const float4*>(xr + 4 * (tq + 4));
    const float4 xb = b0;
    b0 = b1; b1 = b2; b2 = b3;
    if (tq >= 21 && tq < 71) b3 = *reinterpret_cast<const float4*>(xr + 4 * (tq + 4) - 100);
    float4 yo;
    PSPSUB(xa.x, xb.x, yo.x);
    PSPSUB(xa.y, xb.y, yo.y);
    PSPSUB(xa.z, xb.z, yo.z);
    PSPSUB(xa.w, xb.w, yo.w);
    *reinterpret_cast<float4*>(yr + t) = yo;
  }
}

// ---------------- 4x4 sum-pool on raw input (float4 over t), scale 0.6875 ----------------
__global__ __launch_bounds__(256) void pool4_kernel(const float* __restrict__ in,
                                                    float* __restrict__ out) {
  int idx = blockIdx.x * 256 + threadIdx.x;  // quad index
  if (idx >= 153600) return;
  int tq = idx % 75;
  int rest = idx / 75;
  int x = rest & 31; rest >>= 5;
  int y = rest & 31; rest >>= 5;  // rest = bc (0..7)
  const float* base = in + ((long)(rest * 128 + y * 4) * 128 + x * 4) * TLEN + tq * 4;
  float4 s = {0.f, 0.f, 0.f, 0.f};
#pragma unroll
  for (int dy = 0; dy < 4; ++dy)
#pragma unroll
    for (int dx = 0; dx < 4; ++dx) {
      float4 v = *reinterpret_cast<const float4*>(base + (dy * 128 + dx) * TLEN);
      s.x += v.x; s.y += v.y; s.z += v.z; s.w += v.w;
    }
  s.x *= 0.6875f; s.y *= 0.6875f; s.z *= 0.6875f; s.w *= 0.6875f;
  *reinterpret_cast<float4*>(out + ((long)(rest * 32 + y) * 32 + x) * TLEN + tq * 4) = s;
}

// 4-tap x 8-output FMA block; statement order identical to prior verified rounds.
#define FIRSTEP(e, A, B, C)                                                              \
  acc[0] += e.x * B.x; acc[1] += e.x * B.y; acc[2] += e.x * B.z; acc[3] += e.x * B.w;    \
  acc[4] += e.x * C.x; acc[5] += e.x * C.y; acc[6] += e.x * C.z; acc[7] += e.x * C.w;    \
  acc[0] += e.y * A.w; acc[1] += e.y * B.x; acc[2] += e.y * B.y; acc[3] += e.y * B.z;    \
  acc[4] += e.y * B.w; acc[5] += e.y * C.x; acc[6] += e.y * C.y; acc[7] += e.y * C.z;    \
  acc[0] += e.z * A.z; acc[1] += e.z * A.w; acc[2] += e.z * B.x; acc[3] += e.z * B.y;    \
  acc[4] += e.z * B.z; acc[5] += e.z * B.w; acc[6] += e.z * C.x; acc[7] += e.z * C.y;    \
  acc[0] += e.w * A.y; acc[1] += e.w * A.z; acc[2] += e.w * A.w; acc[3] += e.w * B.x;    \
  acc[4] += e.w * B.y; acc[5] += e.w * B.z; acc[6] += e.w * B.w; acc[7] += e.w * C.x;

__device__ __forceinline__ float4 ldq(const float* __restrict__ rowp, int w) {
  if (w >= 0 && w < TLEN) return *reinterpret_cast<const float4*>(rowp + w);
  return make_float4(0.f, 0.f, 0.f, 0.f);
}

// ---------------- direct-from-global 100-tap FIR (L7 psp), 8 outputs/thread ----------
__global__ __launch_bounds__(256) void fir_direct_kernel(const float* __restrict__ in,
                                                         float* __restrict__ out,
                                                         const float* __restrict__ epsg,
                                                         int rows) {
  int task = blockIdx.x * 256 + threadIdx.x;
  int row = task / 38;
  int l = task - row * 38;
  if (row >= rows) return;
  const float* rowp = in + (long)row * TLEN;
  const int t0 = 8 * l;
  float4 A = ldq(rowp, t0 - 4);
  float4 B = ldq(rowp, t0);
  float4 C = ldq(rowp, t0 + 4);
  float acc[8];
#pragma unroll
  for (int j = 0; j < 8; ++j) acc[j] = 0.f;
#pragma unroll 1
  for (int kg0 = 0; kg0 < 80; kg0 += 20) {
    const float* ep = epsg + kg0;
#pragma unroll
    for (int kk = 0; kk < 5; ++kk) {
      const float4 e = *reinterpret_cast<const float4*>(ep + 4 * kk);
      const int kg = kg0 + 4 * kk;
      FIRSTEP(e, A, B, C);
      C = B; B = A;
      A = ldq(rowp, t0 - kg - 8);
    }
    __builtin_amdgcn_sched_barrier(0);
  }
#pragma unroll
  for (int kk = 0; kk < 5; ++kk) {
    const float4 e = *reinterpret_cast<const float4*>(epsg + 80 + 4 * kk);
    FIRSTEP(e, A, B, C);
    C = B; B = A;
    if (kk < 4) A = ldq(rowp, t0 - 88 - 4 * kk);
  }
  float* op = out + (long)row * TLEN + t0;
  *reinterpret_cast<float4*>(op) = make_float4(acc[0], acc[1], acc[2], acc[3]);
  if (t0 + 4 < TLEN)
    *reinterpret_cast<float4*>(op + 4) = make_float4(acc[4], acc[5], acc[6], acc[7]);
}

// ---------------- fc1 4-partial sum + scan -> spikes S5 ----------------
__global__ __launch_bounds__(64) void scan_reduce4_kernel(const float* __restrict__ part,
                                                          float* __restrict__ s) {
  long row = (long)blockIdx.x * 64 + threadIdx.x;  // 2048 rows
  const float* p = part + row * TLEN;
  float* o = s + row * TLEN;
  float ref = 0.f;
#pragma unroll 4
  for (int c4 = 0; c4 < 75; ++c4) {
    const float4 v0 = *reinterpret_cast<const float4*>(p + 4 * c4);
    const float4 v1 = *reinterpret_cast<const float4*>(p + 614400 + 4 * c4);
    const float4 v2 = *reinterpret_cast<const float4*>(p + 1228800 + 4 * c4);
    const float4 v3 = *reinterpret_cast<const float4*>(p + 1843200 + 4 * c4);
    float4 u4;
    u4.x = (v0.x + v1.x) + (v2.x + v3.x);
    u4.y = (v0.y + v1.y) + (v2.y + v3.y);
    u4.z = (v0.z + v1.z) + (v2.z + v3.z);
    u4.w = (v0.w + v1.w) + (v2.w + v3.w);
    float v, sp;
    v = u4.x + ref - THETA; sp = (v >= 0.f) ? 1.f : 0.f; u4.x = sp; ref = REF_DECAY * ref - 20.0f * sp;
    v = u4.y + ref - THETA; sp = (v >= 0.f) ? 1.f : 0.f; u4.y = sp; ref = REF_DECAY * ref - 20.0f * sp;
    v = u4.z + ref - THETA; sp = (v >= 0.f) ? 1.f : 0.f; u4.z = sp; ref = REF_DECAY * ref - 20.0f * sp;
    v = u4.w + ref - THETA; sp = (v >= 0.f) ? 1.f : 0.f; u4.w = sp; ref = REF_DECAY * ref - 20.0f * sp;
    *reinterpret_cast<float4*>(o + 4 * c4) = u4;
  }
}

// ---------------- per-channel delay (lerp gather), C=512, S=1 ----------------
__global__ __launch_bounds__(256) void delay_kernel(const float* __restrict__ in,
                                                    const float* __restrict__ d,
                                                    float* __restrict__ out, int total) {
  int idx = blockIdx.x * 256 + threadIdx.x;
  if (idx >= total) return;
  int t = idx % TLEN;
  int rest = idx / TLEN;  // row = b*512 + c
  float dd = d[rest & 511];
  float src = (float)t - dd;
  float fi = floorf(src);
  int i0 = (int)fi;
  float wf = src - fi;
  const float* base = in + (long)rest * TLEN;
  float v0 = (i0 >= 0 && i0 < TLEN) ? base[min(max(i0, 0), TLEN - 1)] : 0.f;
  float v1 = (i0 + 1 >= 0 && i0 + 1 < TLEN) ? base[min(max(i0 + 1, 0), TLEN - 1)] : 0.f;
  out[idx] = v0 * (1.f - wf) + v1 * wf;
}

// ---------------- fused spike scan + 2x2 pool + per-channel delay (round-5 proven) -------
__device__ __forceinline__ int sqz(int r, int q) { return (q & ~7) | ((q + r) & 7); }

__global__ __launch_bounds__(256) void spike_pool2_delay_kernel(const float* __restrict__ u,
                                                                const float* __restrict__ dly,
                                                                float* __restrict__ out,
                                                                int WI, int C) {
  __shared__ float4 ch[64 * 16];            // chunk: 64 rows x 15 quads (60 t), swizzled
  __shared__ unsigned int bits[64 * 13];    // spike bits, stride 13 (odd)
  const int tid = threadIdx.x;
  const long inrow0 = (long)blockIdx.x * 64;
  float ref = 0.f;
  unsigned int wbits = 0;
  for (int cix = 0; cix < 5; ++cix) {
    __syncthreads();
    for (int i = tid; i < 960; i += 256) {
      int r = i / 15, q = i - r * 15;
      ch[r * 16 + sqz(r, q)] = *reinterpret_cast<const float4*>(
          u + (inrow0 + r) * TLEN + cix * 60 + 4 * q);
    }
    __syncthreads();
    if (tid < 64) {
      int r = tid;
#pragma unroll 1
      for (int q = 0; q < 15; ++q) {
        float4 v = ch[r * 16 + sqz(r, q)];
        int t = cix * 60 + 4 * q;
        float x, sp;
        x = v.x + ref - THETA; sp = (x >= 0.f) ? 1.f : 0.f; ref = REF_DECAY * ref - 20.0f * sp;
        wbits |= ((unsigned int)sp) << (t & 31);
        if ((t & 31) == 31) { bits[r * 13 + (t >> 5)] = wbits; wbits = 0; }
        x = v.y + ref - THETA; sp = (x >= 0.f) ? 1.f : 0.f; ref = REF_DECAY * ref - 20.0f * sp;
        wbits |= ((unsigned int)sp) << ((t + 1) & 31);
        if (((t + 1) & 31) == 31) { bits[r * 13 + ((t + 1) >> 5)] = wbits; wbits = 0; }
        x = v.z + ref - THETA; sp = (x >= 0.f) ? 1.f : 0.f; ref = REF_DECAY * ref - 20.0f * sp;
        wbits |= ((unsigned int)sp) << ((t + 2) & 31);
        if (((t + 2) & 31) == 31) { bits[r * 13 + ((t + 2) >> 5)] = wbits; wbits = 0; }
        x = v.w + ref - THETA; sp = (x >= 0.f) ? 1.f : 0.f; ref = REF_DECAY * ref - 20.0f * sp;
        wbits |= ((unsigned int)sp) << ((t + 3) & 31);
        if (((t + 3) & 31) == 31) { bits[r * 13 + ((t + 3) >> 5)] = wbits; wbits = 0; }
      }
    }
  }
  if (tid < 64) bits[tid * 13 + 9] = wbits;  // final partial word (t=288..299)
  __syncthreads();
  const int WO = WI >> 1;
  const int bc = (int)(inrow0 / (WI * WI));
  const int y0 = (int)((inrow0 % (WI * WI)) / WI);
  const float dd = dly[bc % C];
  const long orow0 = (long)bc * (WO * WO) + (y0 >> 1) * WO;
  for (int i = tid; i < 4800; i += 256) {
    int ro = i / TLEN, t = i - ro * TLEN;
    int Yr = ro / WO, X = ro - Yr * WO;
    int ir = (2 * Yr) * WI + 2 * X;
    float src = (float)t - dd;
    float fi = floorf(src);
    int i0 = (int)fi;
    float wf = src - fi;
    bool ok0 = (i0 >= 0) && (i0 < TLEN);
    bool ok1 = (i0 + 1 >= 0) && (i0 + 1 < TLEN);
    int j0 = min(max(i0, 0), TLEN - 1);
    int j1 = min(max(i0 + 1, 0), TLEN - 1);
    int s0i = 0, s1i = 0;
#pragma unroll
    for (int dy = 0; dy < 2; ++dy)
#pragma unroll
      for (int dx = 0; dx < 2; ++dx) {
        int rr = ir + dy * WI + dx;
        s0i += (int)((bits[rr * 13 + (j0 >> 5)] >> (j0 & 31)) & 1u);
        s1i += (int)((bits[rr * 13 + (j1 >> 5)] >> (j1 & 31)) & 1u);
      }
    float s0 = ok0 ? (float)s0i : 0.f;
    float s1 = ok1 ? (float)s1i : 0.f;
    out[(orow0 + ro) * TLEN + t] = (s0 * (1.f - wf) + s1 * wf) * 2.75f;
  }
}

// ---------------- conv1: 2->16 ch, 5x5, pad 2, 32x32, float4 staging ----------------
__global__ __launch_bounds__(256) void conv1_kernel(const float* __restrict__ in,
                                                    const float* __restrict__ w,
                                                    float* __restrict__ out) {
  __shared__ float xl[11520];  // [c2][dy5][x36][t32]
  const int tid = threadIdx.x;
  const int t0 = blockIdx.x * 32;
  const int y = blockIdx.y;
  const int b = blockIdx.z;
  for (int i = tid; i < 2880; i += 256) {
    int tq = i & 7;
    int rest = i >> 3;
    int xp = rest % 36;
    int r2 = rest / 36;
    int dy = r2 % 5;
    int c = r2 / 5;
    int yy = y + dy - 2, xx = xp - 2, t = t0 + tq * 4;
    float4 v = {0.f, 0.f, 0.f, 0.f};
    if (yy >= 0 && yy < 32 && xx >= 0 && xx < 32 && t < TLEN)
      v = *reinterpret_cast<const float4*>(
          in + ((long)((b * 2 + c) * 32 + yy) * 32 + xx) * TLEN + t);
    *reinterpret_cast<float4*>(&xl[rest * 32 + tq * 4]) = v;
  }
  __syncthreads();
  const int tg = tid & 7;
  const int x = tid >> 3;
  float acc[16][4];
#pragma unroll
  for (int o = 0; o < 16; ++o) { acc[o][0] = acc[o][1] = acc[o][2] = acc[o][3] = 0.f; }
  for (int c = 0; c < 2; ++c)
#pragma unroll
    for (int dy = 0; dy < 5; ++dy)
#pragma unroll
      for (int kx = 0; kx < 5; ++kx) {
        const float4 xv = *reinterpret_cast<const float4*>(
            &xl[((c * 5 + dy) * 36 + x + kx) * 32 + tg * 4]);
        const float* wp = w + (c * 5 + dy) * 5 + kx;
#pragma unroll
        for (int o = 0; o < 16; ++o) {
          float wsc = wp[o * 50];
          acc[o][0] += wsc * xv.x; acc[o][1] += wsc * xv.y;
          acc[o][2] += wsc * xv.z; acc[o][3] += wsc * xv.w;
        }
      }
  const int t = t0 + tg * 4;
  if (t < TLEN) {
#pragma unroll
    for (int o = 0; o < 16; ++o) {
      float4 res; res.x = acc[o][0]; res.y = acc[o][1]; res.z = acc[o][2]; res.w = acc[o][3];
      *reinterpret_cast<float4*>(&out[((long)((b * 16 + o) * 32 + y) * 32 + x) * TLEN + t]) = res;
    }
  }
}

// ---------------- conv2: 16->32 ch, 3x3, pad 1, 16x16, float4 staging ----------------
__global__ __launch_bounds__(256) void conv2_kernel(const float* __restrict__ in,
                                                    const float* __restrict__ w,
                                                    float* __restrict__ out) {
  __shared__ float xl[13824];  // [c16][dy3][x18][t16]
  const int tid = threadIdx.x;
  const int t0 = blockIdx.x * 16;
  const int y = blockIdx.y;
  const int b = blockIdx.z;
  for (int i = tid; i < 3456; i += 256) {
    int tq = i & 3;
    int rest = i >> 2;
    int xp = rest % 18;
    int r2 = rest / 18;
    int dy = r2 % 3;
    int c = r2 / 3;
    int yy = y + dy - 1, xx = xp - 1, t = t0 + tq * 4;
    float4 v = {0.f, 0.f, 0.f, 0.f};
    if (yy >= 0 && yy < 16 && xx >= 0 && xx < 16 && t < TLEN)
      v = *reinterpret_cast<const float4*>(
          in + ((long)((b * 16 + c) * 16 + yy) * 16 + xx) * TLEN + t);
    *reinterpret_cast<float4*>(&xl[rest * 16 + tq * 4]) = v;
  }
  __syncthreads();
  const int tg = tid & 3;
  const int x = (tid >> 2) & 15;
  const int oh = tid >> 6;
  float acc[8][4];
#pragma unroll
  for (int o = 0; o < 8; ++o) { acc[o][0] = acc[o][1] = acc[o][2] = acc[o][3] = 0.f; }
  for (int c = 0; c < 16; ++c)
#pragma unroll
    for (int dy = 0; dy < 3; ++dy)
#pragma unroll
      for (int kx = 0; kx < 3; ++kx) {
        const float4 xv = *reinterpret_cast<const float4*>(
            &xl[((c * 3 + dy) * 18 + x + kx) * 16 + tg * 4]);
        const float* wp = w + (c * 3 + dy) * 3 + kx;
#pragma unroll
        for (int oo = 0; oo < 8; ++oo) {
          float wsc = wp[(oh * 8 + oo) * 144];
          acc[oo][0] += wsc * xv.x; acc[oo][1] += wsc * xv.y;
          acc[oo][2] += wsc * xv.z; acc[oo][3] += wsc * xv.w;
        }
      }
  const int t = t0 + tg * 4;
  if (t < TLEN) {
#pragma unroll
    for (int oo = 0; oo < 8; ++oo) {
      int o = oh * 8 + oo;
      float4 res; res.x = acc[oo][0]; res.y = acc[oo][1]; res.z = acc[oo][2]; res.w = acc[oo][3];
      *reinterpret_cast<float4*>(&out[((long)((b * 32 + o) * 16 + y) * 16 + x) * TLEN + t]) = res;
    }
  }
}

// ---------------- fc1: k-split x4, 64x64 tiles, float4 staging, partials out ----------------
__global__ __launch_bounds__(256) void fc1_kernel(const float* __restrict__ x,
                                                  const float* __restrict__ w,
                                                  float* __restrict__ part) {
  __shared__ float wl[64][44];
  __shared__ float xlb[32][68];
  const int tid = threadIdx.x;
  const int t0 = blockIdx.x * 64;
  const int o0 = blockIdx.y * 64;
  const int b = blockIdx.z >> 2;
  const int split = blockIdx.z & 3;
  const int tx = tid & 15, ty = tid >> 4;
  float acc[4][4];
#pragma unroll
  for (int i = 0; i < 4; ++i)
#pragma unroll
    for (int j = 0; j < 4; ++j) acc[i][j] = 0.f;
  const int kbeg = split * 512;
  for (int kc = kbeg; kc < kbeg + 512; kc += 32) {
    __syncthreads();
#pragma unroll
    for (int rr = 0; rr < 2; ++rr) {
      int i = rr * 256 + tid;
      int ol = i >> 3, kq = i & 7;
      float4 v = *reinterpret_cast<const float4*>(w + (long)(o0 + ol) * 2048 + kc + kq * 4);
      *reinterpret_cast<float4*>(&wl[ol][kq * 4]) = v;
    }
#pragma unroll
    for (int rr = 0; rr < 2; ++rr) {
      int i = rr * 256 + tid;
      int kl = i >> 4, tq = i & 15;
      int t = t0 + tq * 4;
      float4 v = {0.f, 0.f, 0.f, 0.f};
      if (t < TLEN)
        v = *reinterpret_cast<const float4*>(x + ((long)b * 2048 + kc + kl) * TLEN + t);
      *reinterpret_cast<float4*>(&xlb[kl][tq * 4]) = v;
    }
    __syncthreads();
#pragma unroll
    for (int k4 = 0; k4 < 8; ++k4) {
      float4 wq[4], xq[4];
#pragma unroll
      for (int i = 0; i < 4; ++i)
        wq[i] = *reinterpret_cast<const float4*>(&wl[ty * 4 + i][k4 * 4]);
#pragma unroll
      for (int j = 0; j < 4; ++j)
        xq[j] = *reinterpret_cast<const float4*>(&xlb[k4 * 4 + j][tx * 4]);
#pragma unroll
      for (int i = 0; i < 4; ++i) {
        float wa[4] = {wq[i].x, wq[i].y, wq[i].z, wq[i].w};
#pragma unroll
        for (int j = 0; j < 4; ++j) {
          float xa[4] = {xq[j].x, xq[j].y, xq[j].z, xq[j].w};
          acc[i][0] += wa[j] * xa[0]; acc[i][1] += wa[j] * xa[1];
          acc[i][2] += wa[j] * xa[2]; acc[i][3] += wa[j] * xa[3];
        }
      }
    }
  }
  const int t = t0 + tx * 4;
  if (t < TLEN) {
#pragma unroll
    for (int i = 0; i < 4; ++i) {
      float4 res; res.x = acc[i][0]; res.y = acc[i][1]; res.z = acc[i][2]; res.w = acc[i][3];
      *reinterpret_cast<float4*>(
          part + ((long)(split * 4 + b) * 512 + o0 + ty * 4 + i) * TLEN + t) = res;
    }
  }
}

// ---------------- fc2 + final spike scan fused, writes d_out ----------------
__global__ __launch_bounds__(320) void fc2_spike_kernel(const float* __restrict__ x,
                                                        const float* __restrict__ w,
                                                        float* __restrict__ out) {
  __shared__ float ul[304];
  int blk = blockIdx.x;
  int b = blk / 11, o = blk % 11;
  int t = threadIdx.x;
  if (t < TLEN) {
    const float* xr = x + (long)b * 512 * TLEN + t;
    const float* wr = w + o * 512;
    float a0 = 0.f, a1 = 0.f, a2 = 0.f, a3 = 0.f;
#pragma unroll 4
    for (int i = 0; i < 512; i += 4) {
      a0 += wr[i] * xr[(long)i * TLEN];
      a1 += wr[i + 1] * xr[(long)(i + 1) * TLEN];
      a2 += wr[i + 2] * xr[(long)(i + 2) * TLEN];
      a3 += wr[i + 3] * xr[(long)(i + 3) * TLEN];
    }
    ul[t] = (a0 + a1) + (a2 + a3);
  }
  __syncthreads();
  if (t == 0) {
    float ref = 0.f;
#pragma unroll 4
    for (int c = 0; c < TLEN; ++c) {
      float v = ul[c] + ref - THETA;
      float sp = (v >= 0.f) ? 1.f : 0.f;
      ul[c] = sp;
      ref = REF_DECAY * ref - 20.0f * sp;
    }
  }
  __syncthreads();
  if (t < TLEN) out[((long)b * 11 + o) * TLEN + t] = ul[t];
}

extern "C" void kernel_launch(void* const* d_in, const int* in_sizes, int n_in,
                              void* d_out, int out_size, void* d_ws, size_t ws_size,
                              hipStream_t stream) {
  const float* input = (const float*)d_in[0];
  const float* w1    = (const float*)d_in[1];
  const float* w2    = (const float*)d_in[2];
  const float* wfc1  = (const float*)d_in[3];
  const float* wfc2  = (const float*)d_in[4];
  const float* d1    = (const float*)d_in[5];
  const float* d2    = (const float*)d_in[6];
  const float* d3    = (const float*)d_in[7];

  float* ws   = (float*)d_ws;
  float* big0 = ws;                    // conv u (19.66M) / fc1 partials (2.46M)
  float* medA = big0 + 19660800;
  float* medB = medA + 4915200;
  float* fcA  = medB + 4915200;
  float* fcB  = fcA + 614400;
  float* eps  = fcB + 614400;

  hipLaunchKernelGGL(eps_init_kernel, dim3(1), dim3(128), 0, stream, eps);

  // L1: pool4 -> medA; fused psp->spike->psp scan -> medB = psp(S0)
  hipLaunchKernelGGL(pool4_kernel, dim3(600), dim3(256), 0, stream, input, medA);
  hipLaunchKernelGGL(psp_spike_psp_scan_kernel, dim3(128), dim3(64), 0, stream,
                     medA, medB, 8192L);
  // L2: conv1 -> u1 (big0); fused spike+pool2+delay1 -> medA
  hipLaunchKernelGGL(conv1_kernel, dim3(10, 32, 4), dim3(256), 0, stream, medB, w1, big0);
  hipLaunchKernelGGL(spike_pool2_delay_kernel, dim3(1024), dim3(256), 0, stream,
                     big0, d1, medA, 32, 16);
  // L3: fused psp->spike->psp scan -> medB = psp(S2)
  hipLaunchKernelGGL(psp_spike_psp_scan_kernel, dim3(256), dim3(64), 0, stream,
                     medA, medB, 16384L);
  // L4: conv2 -> u3 (big0); fused spike+pool2+delay2 -> medA
  hipLaunchKernelGGL(conv2_kernel, dim3(19, 16, 4), dim3(256), 0, stream, medB, w2, big0);
  hipLaunchKernelGGL(spike_pool2_delay_kernel, dim3(512), dim3(256), 0, stream,
                     big0, d2, medA, 16, 32);
  // L5: fused psp->spike->psp scan -> medB = psp(S4)
  hipLaunchKernelGGL(psp_spike_psp_scan_kernel, dim3(128), dim3(64), 0, stream,
                     medA, medB, 8192L);
  // L6: fc1 -> partials (big0); sum+scan -> S5 (fcA)
  hipLaunchKernelGGL(fc1_kernel, dim3(5, 8, 16), dim3(256), 0, stream, medB, wfc1, big0);
  hipLaunchKernelGGL(scan_reduce4_kernel, dim3(32), dim3(64), 0, stream, big0, fcA);
  // L7: delay3 -> fcB; psp (FIR) -> fcA; fc2+spike -> d_out
  hipLaunchKernelGGL(delay_kernel, dim3(2400), dim3(256), 0, stream, fcA, d3, fcB, 614400);
  hipLaunchKernelGGL(fir_direct_kernel, dim3(304), dim3(256), 0, stream, fcB, fcA, eps, 2048);
  hipLaunchKernelGGL(fc2_spike_kernel, dim3(44), dim3(320), 0, stream, fcA, wfc2, (float*)d_out);
}

// Round 17
// 415.137 us; speedup vs baseline: 2.4508x; 1.0638x over previous
//
#include <hip/hip_runtime.h>

#define TLEN 300
#define THETA 10.0f
#define REF_DECAY 0.36787944117144233f

// Alpha-kernel recurrence constants: eps[k] = C*k*R^k truncated at k<100.
// y[t] = C*QA[t] - C*R^100*QB[t] - 100*C*R^100*PB[t]; (PA,QA) on x[t], (PB,QB) on x[t-100]:
// P[t] = R*P[t-1] + x[t];  Q[t] = R*(Q[t-1] + P[t-1]).
// Round 17: ALL-FLOAT recurrences in the psp scans (reference itself is fp32; contractive
// recurrence keeps steady-state error in the same ~1e-4 class as the reference's own
// summation rounding, which 8 rounds of absmax 0.0 showed is below threshold margins).
#define R_ 0.9048374180359595732
#define C_ 0.2718281828459045235
#define R100_ 4.5399929762484852e-05
#define RF_ ((float)R_)
#define CF_ ((float)C_)
#define CR100F_ ((float)(C_ * R100_))
#define C100R100F_ ((float)(100.0 * C_ * R100_))

// ---------------- eps table (for fir_direct): eps[k] = (k/10)exp(1-k/10) ----------------
__global__ void eps_init_kernel(float* __restrict__ eps) {
  int k = threadIdx.x;
  if (k < 104) eps[k] = 0.f;
  if (k < 100) {
    float a = (float)k / 10.0f;
    eps[k] = a * expf(1.0f - a);
  }
}

// ---------------- fused psp -> spike -> psp scan, one row per lane, all-float ----------
#define PSPSUB(XA, XB, YO)                                                              \
  {                                                                                     \
    QA1 = RF_ * (QA1 + PA1); PA1 = RF_ * PA1 + (XA);                                    \
    QB1 = RF_ * (QB1 + PB1); PB1 = RF_ * PB1 + (XB);                                    \
    float u = CF_ * QA1 - (CR100F_ * QB1 + C100R100F_ * PB1);                           \
    float v = u + ref - THETA;                                                          \
    float sp = (v >= 0.f) ? 1.f : 0.f;                                                  \
    ref = REF_DECAY * ref - 20.0f * sp;                                                 \
    h3 = (h3 << 1) | (h2 >> 31); h2 = (h2 << 1) | (h1 >> 31);                           \
    h1 = (h1 << 1) | (h0 >> 31); h0 = (h0 << 1) | (unsigned)sp;                         \
    float spb = (float)((h3 >> 4) & 1u);                                                \
    QA2 = RF_ * (QA2 + PA2); PA2 = RF_ * PA2 + sp;                                      \
    QB2 = RF_ * (QB2 + PB2); PB2 = RF_ * PB2 + spb;                                     \
    YO = CF_ * QA2 - (CR100F_ * QB2 + C100R100F_ * PB2);                                \
  }

// 4-deep prefetch rings (round-16, neutral but kept) + all-float chain.
__global__ __launch_bounds__(64) void psp_spike_psp_scan_kernel(const float* __restrict__ in,
                                                                float* __restrict__ out,
                                                                long rows) {
  long row = (long)blockIdx.x * 64 + threadIdx.x;
  if (row >= rows) return;
  const float* xr = in + row * TLEN;
  float* yr = out + row * TLEN;
  float PA1 = 0.f, QA1 = 0.f, PA2 = 0.f, QA2 = 0.f;
  float PB1 = 0.f, QB1 = 0.f, PB2 = 0.f, QB2 = 0.f;
  float ref = 0.f;
  unsigned h0 = 0, h1 = 0, h2 = 0, h3 = 0;
  float4 a0 = *reinterpret_cast<const float4*>(xr);
  float4 a1 = *reinterpret_cast<const float4*>(xr + 4);
  float4 a2 = *reinterpret_cast<const float4*>(xr + 8);
  float4 a3 = *reinterpret_cast<const float4*>(xr + 12);
  const float4 z4 = make_float4(0.f, 0.f, 0.f, 0.f);
  float4 b0 = z4, b1 = z4, b2 = z4, b3 = z4;
#pragma unroll 1
  for (int tq = 0; tq < 75; ++tq) {
    const int t = 4 * tq;
    const float4 xa = a0;
    a0 = a1; a1 = a2; a2 = a3;
    if (tq < 71) a3 = *reinterpret_cast<const float4*>(xr + 4 * (tq + 4));
    const float4 xb = b0;
    b0 = b1; b1 = b2; b2 = b3;
    if (tq >= 21 && tq < 71) b3 = *reinterpret_cast<const float4*>(xr + 4 * (tq + 4) - 100);
    float4 yo;
    PSPSUB(xa.x, xb.x, yo.x);
    PSPSUB(xa.y, xb.y, yo.y);
    PSPSUB(xa.z, xb.z, yo.z);
    PSPSUB(xa.w, xb.w, yo.w);
    *reinterpret_cast<float4*>(yr + t) = yo;
  }
}

// ---------------- 4x4 sum-pool on raw input (float4 over t), scale 0.6875 ----------------
__global__ __launch_bounds__(256) void pool4_kernel(const float* __restrict__ in,
                                                    float* __restrict__ out) {
  int idx = blockIdx.x * 256 + threadIdx.x;  // quad index
  if (idx >= 153600) return;
  int tq = idx % 75;
  int rest = idx / 75;
  int x = rest & 31; rest >>= 5;
  int y = rest & 31; rest >>= 5;  // rest = bc (0..7)
  const float* base = in + ((long)(rest * 128 + y * 4) * 128 + x * 4) * TLEN + tq * 4;
  float4 s = {0.f, 0.f, 0.f, 0.f};
#pragma unroll
  for (int dy = 0; dy < 4; ++dy)
#pragma unroll
    for (int dx = 0; dx < 4; ++dx) {
      float4 v = *reinterpret_cast<const float4*>(base + (dy * 128 + dx) * TLEN);
      s.x += v.x; s.y += v.y; s.z += v.z; s.w += v.w;
    }
  s.x *= 0.6875f; s.y *= 0.6875f; s.z *= 0.6875f; s.w *= 0.6875f;
  *reinterpret_cast<float4*>(out + ((long)(rest * 32 + y) * 32 + x) * TLEN + tq * 4) = s;
}

// 4-tap x 8-output FMA block; statement order identical to prior verified rounds.
#define FIRSTEP(e, A, B, C)                                                              \
  acc[0] += e.x * B.x; acc[1] += e.x * B.y; acc[2] += e.x * B.z; acc[3] += e.x * B.w;    \
  acc[4] += e.x * C.x; acc[5] += e.x * C.y; acc[6] += e.x * C.z; acc[7] += e.x * C.w;    \
  acc[0] += e.y * A.w; acc[1] += e.y * B.x; acc[2] += e.y * B.y; acc[3] += e.y * B.z;    \
  acc[4] += e.y * B.w; acc[5] += e.y * C.x; acc[6] += e.y * C.y; acc[7] += e.y * C.z;    \
  acc[0] += e.z * A.z; acc[1] += e.z * A.w; acc[2] += e.z * B.x; acc[3] += e.z * B.y;    \
  acc[4] += e.z * B.z; acc[5] += e.z * B.w; acc[6] += e.z * C.x; acc[7] += e.z * C.y;    \
  acc[0] += e.w * A.y; acc[1] += e.w * A.z; acc[2] += e.w * A.w; acc[3] += e.w * B.x;    \
  acc[4] += e.w * B.y; acc[5] += e.w * B.z; acc[6] += e.w * B.w; acc[7] += e.w * C.x;

__device__ __forceinline__ float4 ldq(const float* __restrict__ rowp, int w) {
  if (w >= 0 && w < TLEN) return *reinterpret_cast<const float4*>(rowp + w);
  return make_float4(0.f, 0.f, 0.f, 0.f);
}

// ---------------- direct-from-global 100-tap FIR (L7 psp), 8 outputs/thread ----------
__global__ __launch_bounds__(256) void fir_direct_kernel(const float* __restrict__ in,
                                                         float* __restrict__ out,
                                                         const float* __restrict__ epsg,
                                                         int rows) {
  int task = blockIdx.x * 256 + threadIdx.x;
  int row = task / 38;
  int l = task - row * 38;
  if (row >= rows) return;
  const float* rowp = in + (long)row * TLEN;
  const int t0 = 8 * l;
  float4 A = ldq(rowp, t0 - 4);
  float4 B = ldq(rowp, t0);
  float4 C = ldq(rowp, t0 + 4);
  float acc[8];
#pragma unroll
  for (int j = 0; j < 8; ++j) acc[j] = 0.f;
#pragma unroll 1
  for (int kg0 = 0; kg0 < 80; kg0 += 20) {
    const float* ep = epsg + kg0;
#pragma unroll
    for (int kk = 0; kk < 5; ++kk) {
      const float4 e = *reinterpret_cast<const float4*>(ep + 4 * kk);
      const int kg = kg0 + 4 * kk;
      FIRSTEP(e, A, B, C);
      C = B; B = A;
      A = ldq(rowp, t0 - kg - 8);
    }
    __builtin_amdgcn_sched_barrier(0);
  }
#pragma unroll
  for (int kk = 0; kk < 5; ++kk) {
    const float4 e = *reinterpret_cast<const float4*>(epsg + 80 + 4 * kk);
    FIRSTEP(e, A, B, C);
    C = B; B = A;
    if (kk < 4) A = ldq(rowp, t0 - 88 - 4 * kk);
  }
  float* op = out + (long)row * TLEN + t0;
  *reinterpret_cast<float4*>(op) = make_float4(acc[0], acc[1], acc[2], acc[3]);
  if (t0 + 4 < TLEN)
    *reinterpret_cast<float4*>(op + 4) = make_float4(acc[4], acc[5], acc[6], acc[7]);
}

// ---------------- fc1 4-partial sum + scan -> spikes S5 ----------------
__global__ __launch_bounds__(64) void scan_reduce4_kernel(const float* __restrict__ part,
                                                          float* __restrict__ s) {
  long row = (long)blockIdx.x * 64 + threadIdx.x;  // 2048 rows
  const float* p = part + row * TLEN;
  float* o = s + row * TLEN;
  float ref = 0.f;
#pragma unroll 4
  for (int c4 = 0; c4 < 75; ++c4) {
    const float4 v0 = *reinterpret_cast<const float4*>(p + 4 * c4);
    const float4 v1 = *reinterpret_cast<const float4*>(p + 614400 + 4 * c4);
    const float4 v2 = *reinterpret_cast<const float4*>(p + 1228800 + 4 * c4);
    const float4 v3 = *reinterpret_cast<const float4*>(p + 1843200 + 4 * c4);
    float4 u4;
    u4.x = (v0.x + v1.x) + (v2.x + v3.x);
    u4.y = (v0.y + v1.y) + (v2.y + v3.y);
    u4.z = (v0.z + v1.z) + (v2.z + v3.z);
    u4.w = (v0.w + v1.w) + (v2.w + v3.w);
    float v, sp;
    v = u4.x + ref - THETA; sp = (v >= 0.f) ? 1.f : 0.f; u4.x = sp; ref = REF_DECAY * ref - 20.0f * sp;
    v = u4.y + ref - THETA; sp = (v >= 0.f) ? 1.f : 0.f; u4.y = sp; ref = REF_DECAY * ref - 20.0f * sp;
    v = u4.z + ref - THETA; sp = (v >= 0.f) ? 1.f : 0.f; u4.z = sp; ref = REF_DECAY * ref - 20.0f * sp;
    v = u4.w + ref - THETA; sp = (v >= 0.f) ? 1.f : 0.f; u4.w = sp; ref = REF_DECAY * ref - 20.0f * sp;
    *reinterpret_cast<float4*>(o + 4 * c4) = u4;
  }
}

// ---------------- per-channel delay (lerp gather), C=512, S=1 ----------------
__global__ __launch_bounds__(256) void delay_kernel(const float* __restrict__ in,
                                                    const float* __restrict__ d,
                                                    float* __restrict__ out, int total) {
  int idx = blockIdx.x * 256 + threadIdx.x;
  if (idx >= total) return;
  int t = idx % TLEN;
  int rest = idx / TLEN;  // row = b*512 + c
  float dd = d[rest & 511];
  float src = (float)t - dd;
  float fi = floorf(src);
  int i0 = (int)fi;
  float wf = src - fi;
  const float* base = in + (long)rest * TLEN;
  float v0 = (i0 >= 0 && i0 < TLEN) ? base[min(max(i0, 0), TLEN - 1)] : 0.f;
  float v1 = (i0 + 1 >= 0 && i0 + 1 < TLEN) ? base[min(max(i0 + 1, 0), TLEN - 1)] : 0.f;
  out[idx] = v0 * (1.f - wf) + v1 * wf;
}

// ---------------- fused spike scan + 2x2 pool + per-channel delay (round-5 proven) -------
__device__ __forceinline__ int sqz(int r, int q) { return (q & ~7) | ((q + r) & 7); }

__global__ __launch_bounds__(256) void spike_pool2_delay_kernel(const float* __restrict__ u,
                                                                const float* __restrict__ dly,
                                                                float* __restrict__ out,
                                                                int WI, int C) {
  __shared__ float4 ch[64 * 16];            // chunk: 64 rows x 15 quads (60 t), swizzled
  __shared__ unsigned int bits[64 * 13];    // spike bits, stride 13 (odd)
  const int tid = threadIdx.x;
  const long inrow0 = (long)blockIdx.x * 64;
  float ref = 0.f;
  unsigned int wbits = 0;
  for (int cix = 0; cix < 5; ++cix) {
    __syncthreads();
    for (int i = tid; i < 960; i += 256) {
      int r = i / 15, q = i - r * 15;
      ch[r * 16 + sqz(r, q)] = *reinterpret_cast<const float4*>(
          u + (inrow0 + r) * TLEN + cix * 60 + 4 * q);
    }
    __syncthreads();
    if (tid < 64) {
      int r = tid;
#pragma unroll 1
      for (int q = 0; q < 15; ++q) {
        float4 v = ch[r * 16 + sqz(r, q)];
        int t = cix * 60 + 4 * q;
        float x, sp;
        x = v.x + ref - THETA; sp = (x >= 0.f) ? 1.f : 0.f; ref = REF_DECAY * ref - 20.0f * sp;
        wbits |= ((unsigned int)sp) << (t & 31);
        if ((t & 31) == 31) { bits[r * 13 + (t >> 5)] = wbits; wbits = 0; }
        x = v.y + ref - THETA; sp = (x >= 0.f) ? 1.f : 0.f; ref = REF_DECAY * ref - 20.0f * sp;
        wbits |= ((unsigned int)sp) << ((t + 1) & 31);
        if (((t + 1) & 31) == 31) { bits[r * 13 + ((t + 1) >> 5)] = wbits; wbits = 0; }
        x = v.z + ref - THETA; sp = (x >= 0.f) ? 1.f : 0.f; ref = REF_DECAY * ref - 20.0f * sp;
        wbits |= ((unsigned int)sp) << ((t + 2) & 31);
        if (((t + 2) & 31) == 31) { bits[r * 13 + ((t + 2) >> 5)] = wbits; wbits = 0; }
        x = v.w + ref - THETA; sp = (x >= 0.f) ? 1.f : 0.f; ref = REF_DECAY * ref - 20.0f * sp;
        wbits |= ((unsigned int)sp) << ((t + 3) & 31);
        if (((t + 3) & 31) == 31) { bits[r * 13 + ((t + 3) >> 5)] = wbits; wbits = 0; }
      }
    }
  }
  if (tid < 64) bits[tid * 13 + 9] = wbits;  // final partial word (t=288..299)
  __syncthreads();
  const int WO = WI >> 1;
  const int bc = (int)(inrow0 / (WI * WI));
  const int y0 = (int)((inrow0 % (WI * WI)) / WI);
  const float dd = dly[bc % C];
  const long orow0 = (long)bc * (WO * WO) + (y0 >> 1) * WO;
  for (int i = tid; i < 4800; i += 256) {
    int ro = i / TLEN, t = i - ro * TLEN;
    int Yr = ro / WO, X = ro - Yr * WO;
    int ir = (2 * Yr) * WI + 2 * X;
    float src = (float)t - dd;
    float fi = floorf(src);
    int i0 = (int)fi;
    float wf = src - fi;
    bool ok0 = (i0 >= 0) && (i0 < TLEN);
    bool ok1 = (i0 + 1 >= 0) && (i0 + 1 < TLEN);
    int j0 = min(max(i0, 0), TLEN - 1);
    int j1 = min(max(i0 + 1, 0), TLEN - 1);
    int s0i = 0, s1i = 0;
#pragma unroll
    for (int dy = 0; dy < 2; ++dy)
#pragma unroll
      for (int dx = 0; dx < 2; ++dx) {
        int rr = ir + dy * WI + dx;
        s0i += (int)((bits[rr * 13 + (j0 >> 5)] >> (j0 & 31)) & 1u);
        s1i += (int)((bits[rr * 13 + (j1 >> 5)] >> (j1 & 31)) & 1u);
      }
    float s0 = ok0 ? (float)s0i : 0.f;
    float s1 = ok1 ? (float)s1i : 0.f;
    out[(orow0 + ro) * TLEN + t] = (s0 * (1.f - wf) + s1 * wf) * 2.75f;
  }
}

// ---------------- conv1: 2->16 ch, 5x5, pad 2, 32x32, float4 staging ----------------
__global__ __launch_bounds__(256) void conv1_kernel(const float* __restrict__ in,
                                                    const float* __restrict__ w,
                                                    float* __restrict__ out) {
  __shared__ float xl[11520];  // [c2][dy5][x36][t32]
  const int tid = threadIdx.x;
  const int t0 = blockIdx.x * 32;
  const int y = blockIdx.y;
  const int b = blockIdx.z;
  for (int i = tid; i < 2880; i += 256) {
    int tq = i & 7;
    int rest = i >> 3;
    int xp = rest % 36;
    int r2 = rest / 36;
    int dy = r2 % 5;
    int c = r2 / 5;
    int yy = y + dy - 2, xx = xp - 2, t = t0 + tq * 4;
    float4 v = {0.f, 0.f, 0.f, 0.f};
    if (yy >= 0 && yy < 32 && xx >= 0 && xx < 32 && t < TLEN)
      v = *reinterpret_cast<const float4*>(
          in + ((long)((b * 2 + c) * 32 + yy) * 32 + xx) * TLEN + t);
    *reinterpret_cast<float4*>(&xl[rest * 32 + tq * 4]) = v;
  }
  __syncthreads();
  const int tg = tid & 7;
  const int x = tid >> 3;
  float acc[16][4];
#pragma unroll
  for (int o = 0; o < 16; ++o) { acc[o][0] = acc[o][1] = acc[o][2] = acc[o][3] = 0.f; }
  for (int c = 0; c < 2; ++c)
#pragma unroll
    for (int dy = 0; dy < 5; ++dy)
#pragma unroll
      for (int kx = 0; kx < 5; ++kx) {
        const float4 xv = *reinterpret_cast<const float4*>(
            &xl[((c * 5 + dy) * 36 + x + kx) * 32 + tg * 4]);
        const float* wp = w + (c * 5 + dy) * 5 + kx;
#pragma unroll
        for (int o = 0; o < 16; ++o) {
          float wsc = wp[o * 50];
          acc[o][0] += wsc * xv.x; acc[o][1] += wsc * xv.y;
          acc[o][2] += wsc * xv.z; acc[o][3] += wsc * xv.w;
        }
      }
  const int t = t0 + tg * 4;
  if (t < TLEN) {
#pragma unroll
    for (int o = 0; o < 16; ++o) {
      float4 res; res.x = acc[o][0]; res.y = acc[o][1]; res.z = acc[o][2]; res.w = acc[o][3];
      *reinterpret_cast<float4*>(&out[((long)((b * 16 + o) * 32 + y) * 32 + x) * TLEN + t]) = res;
    }
  }
}

// ---------------- conv2: 16->32 ch, 3x3, pad 1, 16x16, float4 staging ----------------
__global__ __launch_bounds__(256) void conv2_kernel(const float* __restrict__ in,
                                                    const float* __restrict__ w,
                                                    float* __restrict__ out) {
  __shared__ float xl[13824];  // [c16][dy3][x18][t16]
  const int tid = threadIdx.x;
  const int t0 = blockIdx.x * 16;
  const int y = blockIdx.y;
  const int b = blockIdx.z;
  for (int i = tid; i < 3456; i += 256) {
    int tq = i & 3;
    int rest = i >> 2;
    int xp = rest % 18;
    int r2 = rest / 18;
    int dy = r2 % 3;
    int c = r2 / 3;
    int yy = y + dy - 1, xx = xp - 1, t = t0 + tq * 4;
    float4 v = {0.f, 0.f, 0.f, 0.f};
    if (yy >= 0 && yy < 16 && xx >= 0 && xx < 16 && t < TLEN)
      v = *reinterpret_cast<const float4*>(
          in + ((long)((b * 16 + c) * 16 + yy) * 16 + xx) * TLEN + t);
    *reinterpret_cast<float4*>(&xl[rest * 16 + tq * 4]) = v;
  }
  __syncthreads();
  const int tg = tid & 3;
  const int x = (tid >> 2) & 15;
  const int oh = tid >> 6;
  float acc[8][4];
#pragma unroll
  for (int o = 0; o < 8; ++o) { acc[o][0] = acc[o][1] = acc[o][2] = acc[o][3] = 0.f; }
  for (int c = 0; c < 16; ++c)
#pragma unroll
    for (int dy = 0; dy < 3; ++dy)
#pragma unroll
      for (int kx = 0; kx < 3; ++kx) {
        const float4 xv = *reinterpret_cast<const float4*>(
            &xl[((c * 3 + dy) * 18 + x + kx) * 16 + tg * 4]);
        const float* wp = w + (c * 3 + dy) * 3 + kx;
#pragma unroll
        for (int oo = 0; oo < 8; ++oo) {
          float wsc = wp[(oh * 8 + oo) * 144];
          acc[oo][0] += wsc * xv.x; acc[oo][1] += wsc * xv.y;
          acc[oo][2] += wsc * xv.z; acc[oo][3] += wsc * xv.w;
        }
      }
  const int t = t0 + tg * 4;
  if (t < TLEN) {
#pragma unroll
    for (int oo = 0; oo < 8; ++oo) {
      int o = oh * 8 + oo;
      float4 res; res.x = acc[oo][0]; res.y = acc[oo][1]; res.z = acc[oo][2]; res.w = acc[oo][3];
      *reinterpret_cast<float4*>(&out[((long)((b * 32 + o) * 16 + y) * 16 + x) * TLEN + t]) = res;
    }
  }
}

// ---------------- fc1: k-split x4, 64x64 tiles, float4 staging, partials out ----------------
__global__ __launch_bounds__(256) void fc1_kernel(const float* __restrict__ x,
                                                  const float* __restrict__ w,
                                                  float* __restrict__ part) {
  __shared__ float wl[64][44];
  __shared__ float xlb[32][68];
  const int tid = threadIdx.x;
  const int t0 = blockIdx.x * 64;
  const int o0 = blockIdx.y * 64;
  const int b = blockIdx.z >> 2;
  const int split = blockIdx.z & 3;
  const int tx = tid & 15, ty = tid >> 4;
  float acc[4][4];
#pragma unroll
  for (int i = 0; i < 4; ++i)
#pragma unroll
    for (int j = 0; j < 4; ++j) acc[i][j] = 0.f;
  const int kbeg = split * 512;
  for (int kc = kbeg; kc < kbeg + 512; kc += 32) {
    __syncthreads();
#pragma unroll
    for (int rr = 0; rr < 2; ++rr) {
      int i = rr * 256 + tid;
      int ol = i >> 3, kq = i & 7;
      float4 v = *reinterpret_cast<const float4*>(w + (long)(o0 + ol) * 2048 + kc + kq * 4);
      *reinterpret_cast<float4*>(&wl[ol][kq * 4]) = v;
    }
#pragma unroll
    for (int rr = 0; rr < 2; ++rr) {
      int i = rr * 256 + tid;
      int kl = i >> 4, tq = i & 15;
      int t = t0 + tq * 4;
      float4 v = {0.f, 0.f, 0.f, 0.f};
      if (t < TLEN)
        v = *reinterpret_cast<const float4*>(x + ((long)b * 2048 + kc + kl) * TLEN + t);
      *reinterpret_cast<float4*>(&xlb[kl][tq * 4]) = v;
    }
    __syncthreads();
#pragma unroll
    for (int k4 = 0; k4 < 8; ++k4) {
      float4 wq[4], xq[4];
#pragma unroll
      for (int i = 0; i < 4; ++i)
        wq[i] = *reinterpret_cast<const float4*>(&wl[ty * 4 + i][k4 * 4]);
#pragma unroll
      for (int j = 0; j < 4; ++j)
        xq[j] = *reinterpret_cast<const float4*>(&xlb[k4 * 4 + j][tx * 4]);
#pragma unroll
      for (int i = 0; i < 4; ++i) {
        float wa[4] = {wq[i].x, wq[i].y, wq[i].z, wq[i].w};
#pragma unroll
        for (int j = 0; j < 4; ++j) {
          float xa[4] = {xq[j].x, xq[j].y, xq[j].z, xq[j].w};
          acc[i][0] += wa[j] * xa[0]; acc[i][1] += wa[j] * xa[1];
          acc[i][2] += wa[j] * xa[2]; acc[i][3] += wa[j] * xa[3];
        }
      }
    }
  }
  const int t = t0 + tx * 4;
  if (t < TLEN) {
#pragma unroll
    for (int i = 0; i < 4; ++i) {
      float4 res; res.x = acc[i][0]; res.y = acc[i][1]; res.z = acc[i][2]; res.w = acc[i][3];
      *reinterpret_cast<float4*>(
          part + ((long)(split * 4 + b) * 512 + o0 + ty * 4 + i) * TLEN + t) = res;
    }
  }
}

// ---------------- fc2 + final spike scan fused, writes d_out ----------------
__global__ __launch_bounds__(320) void fc2_spike_kernel(const float* __restrict__ x,
                                                        const float* __restrict__ w,
                                                        float* __restrict__ out) {
  __shared__ float ul[304];
  int blk = blockIdx.x;
  int b = blk / 11, o = blk % 11;
  int t = threadIdx.x;
  if (t < TLEN) {
    const float* xr = x + (long)b * 512 * TLEN + t;
    const float* wr = w + o * 512;
    float a0 = 0.f, a1 = 0.f, a2 = 0.f, a3 = 0.f;
#pragma unroll 4
    for (int i = 0; i < 512; i += 4) {
      a0 += wr[i] * xr[(long)i * TLEN];
      a1 += wr[i + 1] * xr[(long)(i + 1) * TLEN];
      a2 += wr[i + 2] * xr[(long)(i + 2) * TLEN];
      a3 += wr[i + 3] * xr[(long)(i + 3) * TLEN];
    }
    ul[t] = (a0 + a1) + (a2 + a3);
  }
  __syncthreads();
  if (t == 0) {
    float ref = 0.f;
#pragma unroll 4
    for (int c = 0; c < TLEN; ++c) {
      float v = ul[c] + ref - THETA;
      float sp = (v >= 0.f) ? 1.f : 0.f;
      ul[c] = sp;
      ref = REF_DECAY * ref - 20.0f * sp;
    }
  }
  __syncthreads();
  if (t < TLEN) out[((long)b * 11 + o) * TLEN + t] = ul[t];
}

extern "C" void kernel_launch(void* const* d_in, const int* in_sizes, int n_in,
                              void* d_out, int out_size, void* d_ws, size_t ws_size,
                              hipStream_t stream) {
  const float* input = (const float*)d_in[0];
  const float* w1    = (const float*)d_in[1];
  const float* w2    = (const float*)d_in[2];
  const float* wfc1  = (const float*)d_in[3];
  const float* wfc2  = (const float*)d_in[4];
  const float* d1    = (const float*)d_in[5];
  const float* d2    = (const float*)d_in[6];
  const float* d3    = (const float*)d_in[7];

  float* ws   = (float*)d_ws;
  float* big0 = ws;                    // conv u (19.66M) / fc1 partials (2.46M)
  float* medA = big0 + 19660800;
  float* medB = medA + 4915200;
  float* fcA  = medB + 4915200;
  float* fcB  = fcA + 614400;
  float* eps  = fcB + 614400;

  hipLaunchKernelGGL(eps_init_kernel, dim3(1), dim3(128), 0, stream, eps);

  // L1: pool4 -> medA; fused psp->spike->psp scan -> medB = psp(S0)
  hipLaunchKernelGGL(pool4_kernel, dim3(600), dim3(256), 0, stream, input, medA);
  hipLaunchKernelGGL(psp_spike_psp_scan_kernel, dim3(128), dim3(64), 0, stream,
                     medA, medB, 8192L);
  // L2: conv1 -> u1 (big0); fused spike+pool2+delay1 -> medA
  hipLaunchKernelGGL(conv1_kernel, dim3(10, 32, 4), dim3(256), 0, stream, medB, w1, big0);
  hipLaunchKernelGGL(spike_pool2_delay_kernel, dim3(1024), dim3(256), 0, stream,
                     big0, d1, medA, 32, 16);
  // L3: fused psp->spike->psp scan -> medB = psp(S2)
  hipLaunchKernelGGL(psp_spike_psp_scan_kernel, dim3(256), dim3(64), 0, stream,
                     medA, medB, 16384L);
  // L4: conv2 -> u3 (big0); fused spike+pool2+delay2 -> medA
  hipLaunchKernelGGL(conv2_kernel, dim3(19, 16, 4), dim3(256), 0, stream, medB, w2, big0);
  hipLaunchKernelGGL(spike_pool2_delay_kernel, dim3(512), dim3(256), 0, stream,
                     big0, d2, medA, 16, 32);
  // L5: fused psp->spike->psp scan -> medB = psp(S4)
  hipLaunchKernelGGL(psp_spike_psp_scan_kernel, dim3(128), dim3(64), 0, stream,
                     medA, medB, 8192L);
  // L6: fc1 -> partials (big0); sum+scan -> S5 (fcA)
  hipLaunchKernelGGL(fc1_kernel, dim3(5, 8, 16), dim3(256), 0, stream, medB, wfc1, big0);
  hipLaunchKernelGGL(scan_reduce4_kernel, dim3(32), dim3(64), 0, stream, big0, fcA);
  // L7: delay3 -> fcB; psp (FIR) -> fcA; fc2+spike -> d_out
  hipLaunchKernelGGL(delay_kernel, dim3(2400), dim3(256), 0, stream, fcA, d3, fcB, 614400);
  hipLaunchKernelGGL(fir_direct_kernel, dim3(304), dim3(256), 0, stream, fcB, fcA, eps, 2048);
  hipLaunchKernelGGL(fc2_spike_kernel, dim3(44), dim3(320), 0, stream, fcA, wfc2, (float*)d_out);
}